// Round 1
// baseline (3822.994 us; speedup 1.0000x reference)
//
#include <hip/hip_runtime.h>
#include <hip/hip_bf16.h>
#include <math.h>

#define HIDDEN    64
#define N_NODES   100000
#define N_EDGES   1250000
#define EDGE_FEAT 13

// ---------------- workspace layout (bytes) ----------------
// w     : E floats        @ 0            (5,000,000 B)
// dinv  : N floats        @ 5,000,000    (400,000 B)   (holds deg first, then rsqrt in place)
// bufA  : N*64 floats     @ 5,400,000    (25,600,000 B)
// bufB  : N*64 floats     @ 31,000,000   (25,600,000 B)
// acc   : 3*68 floats     @ 56,600,000   (816 B)  per layer: [0..63]=vec, [64]=sum
#define OFF_W    0
#define OFF_DEG  5000000
#define OFF_A    5400000
#define OFF_B    31000000
#define OFF_ACC  56600000

// deg[n] = 1.0 (self-loop weight)
__global__ void init_deg(float* __restrict__ deg, int n) {
    int i = blockIdx.x * blockDim.x + threadIdx.x;
    if (i < n) deg[i] = 1.0f;
}

// per-edge weight = edge_attr . softmax(aaaaa); atomic deg[col] += w
__global__ void edgew_kernel(const float* __restrict__ attr,
                             const int* __restrict__ cols,
                             const float* __restrict__ aaaaa,
                             float* __restrict__ w,
                             float* __restrict__ deg, int E) {
    __shared__ float s[EDGE_FEAT];
    if (threadIdx.x == 0) {
        float m = -1e30f;
        for (int i = 0; i < EDGE_FEAT; i++) m = fmaxf(m, aaaaa[i]);
        float ex[EDGE_FEAT]; float sum = 0.f;
        for (int i = 0; i < EDGE_FEAT; i++) { ex[i] = __expf(aaaaa[i] - m); sum += ex[i]; }
        float inv = 1.f / sum;
        for (int i = 0; i < EDGE_FEAT; i++) s[i] = ex[i] * inv;
    }
    __syncthreads();
    int e = blockIdx.x * blockDim.x + threadIdx.x;
    if (e >= E) return;
    const float* a = attr + (size_t)e * EDGE_FEAT;
    float acc = 0.f;
#pragma unroll
    for (int f = 0; f < EDGE_FEAT; f++) acc = fmaf(a[f], s[f], acc);
    w[e] = acc;
    atomicAdd(&deg[cols[e]], acc);
}

__global__ void dinv_kernel(float* __restrict__ deg, int n) {
    int i = blockIdx.x * blockDim.x + threadIdx.x;
    if (i < n) {
        float d = deg[i];
        deg[i] = (d > 0.f) ? rsqrtf(d) : 0.f;
    }
}

// B[r,c] = sum_k A[r,k] * W[k,c]   (64x64 W staged in LDS; 64 rows/block)
__global__ __launch_bounds__(256) void gemm64(const float* __restrict__ A,
                                              const float* __restrict__ W,
                                              float* __restrict__ B, int N) {
    __shared__ float Ws[HIDDEN * HIDDEN];
    int tid = threadIdx.x;
    for (int i = tid; i < HIDDEN * HIDDEN; i += 256) Ws[i] = W[i];
    __syncthreads();
    int r = blockIdx.x * 64 + (tid >> 2);
    int c0 = (tid & 3) * 16;
    if (r >= N) return;
    const float* a = A + (size_t)r * HIDDEN;
    float acc[16];
#pragma unroll
    for (int j = 0; j < 16; j++) acc[j] = 0.f;
    for (int k = 0; k < HIDDEN; k++) {
        float av = a[k];
        const float* wrow = &Ws[k * HIDDEN + c0];
#pragma unroll
        for (int j = 0; j < 16; j++) acc[j] = fmaf(av, wrow[j], acc[j]);
    }
    float* b = B + (size_t)r * HIDDEN + c0;
#pragma unroll
    for (int j = 0; j < 16; j++) b[j] = acc[j];
}

// out[col] += dinv[row]*w*dinv[col] * h[row] ; 16 threads/edge, float4 gather
__global__ void scatter_kernel(const float* __restrict__ h,
                               const int* __restrict__ rows,
                               const int* __restrict__ cols,
                               const float* __restrict__ w,
                               const float* __restrict__ dinv,
                               float* __restrict__ out, int E) {
    long long t = (long long)blockIdx.x * blockDim.x + threadIdx.x;
    int e = (int)(t >> 4);
    if (e >= E) return;
    int j = ((int)t & 15) * 4;
    int r = rows[e], c = cols[e];
    float norm = dinv[r] * w[e] * dinv[c];
    const float4 hv = *(const float4*)(h + (size_t)r * HIDDEN + j);
    float* o = out + (size_t)c * HIDDEN + j;
    atomicAdd(o + 0, norm * hv.x);
    atomicAdd(o + 1, norm * hv.y);
    atomicAdd(o + 2, norm * hv.z);
    atomicAdd(o + 3, norm * hv.w);
}

// out = relu(out + dinv[n]^2 * h + b)   (self-loop + bias + relu, in place)
__global__ void finish_kernel(const float* __restrict__ h,
                              const float* __restrict__ dinv,
                              const float* __restrict__ b,
                              float* __restrict__ out, int N) {
    long long t = (long long)blockIdx.x * blockDim.x + threadIdx.x;
    int n = (int)(t >> 4);
    if (n >= N) return;
    int j = ((int)t & 15) * 4;
    float di = dinv[n];
    float d2 = di * di;
    float4 hv = *(const float4*)(h + (size_t)n * HIDDEN + j);
    float4 ov = *(float4*)(out + (size_t)n * HIDDEN + j);
    float4 bv = *(const float4*)(b + j);
    ov.x = fmaxf(fmaf(d2, hv.x, ov.x) + bv.x, 0.f);
    ov.y = fmaxf(fmaf(d2, hv.y, ov.y) + bv.y, 0.f);
    ov.z = fmaxf(fmaf(d2, hv.z, ov.z) + bv.z, 0.f);
    ov.w = fmaxf(fmaf(d2, hv.w, ov.w) + bv.w, 0.f);
    *(float4*)(out + (size_t)n * HIDDEN + j) = ov;
}

// attention pool: acc[0..63] += sum_n exp(sigmoid(x_n.wg+bg)) * x_n ; acc[64] += sum exp(...)
__global__ void pool_kernel(const float* __restrict__ x,
                            const float* __restrict__ wg,
                            const float* __restrict__ bg,
                            float* __restrict__ acc, int N) {
    int lane = threadIdx.x & 63;
    int wave = (int)(((long long)blockIdx.x * blockDim.x + threadIdx.x) >> 6);
    int nwaves = (gridDim.x * blockDim.x) >> 6;
    float wgv = wg[lane];
    float bg0 = bg[0];
    float accv = 0.f, accs = 0.f;
    for (int n = wave; n < N; n += nwaves) {
        float xv = x[(size_t)n * HIDDEN + lane];
        float p = xv * wgv;
#pragma unroll
        for (int m = 32; m > 0; m >>= 1) p += __shfl_xor(p, m, 64);
        float g = 1.f / (1.f + __expf(-(p + bg0)));
        float e = __expf(g);
        accv = fmaf(e, xv, accv);
        accs += e;
    }
    atomicAdd(&acc[lane], accv);
    if (lane == 0) atomicAdd(&acc[64], accs * (1.f / 1.f));  // accs counted once per lane? no: see below
}

// NOTE on accs: every lane accumulates the same e (post-reduction broadcast), so
// lane 0's accs alone is the correct per-wave sum. We only atomically add lane 0's.

__global__ void finalize_kernel(const float* __restrict__ acc, float* __restrict__ out) {
    int i = threadIdx.x;  // 192 threads
    if (i >= 3 * HIDDEN) return;
    int layer = i >> 6, c = i & 63;
    const float* a = acc + layer * 68;
    out[i] = a[c] / a[64];
}

extern "C" void kernel_launch(void* const* d_in, const int* in_sizes, int n_in,
                              void* d_out, int out_size, void* d_ws, size_t ws_size,
                              hipStream_t stream) {
    const float* x         = (const float*)d_in[0];
    const int*   edge_index= (const int*)  d_in[1];   // [2,E] flat: rows then cols
    const float* edge_attr = (const float*)d_in[2];
    const float* aaaaa     = (const float*)d_in[3];
    const float* W1 = (const float*)d_in[4];  const float* b1 = (const float*)d_in[5];
    const float* W2 = (const float*)d_in[6];  const float* b2 = (const float*)d_in[7];
    const float* W3 = (const float*)d_in[8];  const float* b3 = (const float*)d_in[9];
    const float* wg1 = (const float*)d_in[10]; const float* bg1 = (const float*)d_in[11];
    const float* wg2 = (const float*)d_in[12]; const float* bg2 = (const float*)d_in[13];
    const float* wg3 = (const float*)d_in[14]; const float* bg3 = (const float*)d_in[15];
    float* out = (float*)d_out;

    char* ws = (char*)d_ws;
    float* w    = (float*)(ws + OFF_W);
    float* dinv = (float*)(ws + OFF_DEG);
    float* bufA = (float*)(ws + OFF_A);
    float* bufB = (float*)(ws + OFF_B);
    float* acc  = (float*)(ws + OFF_ACC);

    const int* rows = edge_index;
    const int* cols = edge_index + N_EDGES;

    const int N = N_NODES, E = N_EDGES;

    // zero pool accumulators
    hipMemsetAsync(acc, 0, 3 * 68 * sizeof(float), stream);

    // degrees (self-loop = 1.0) + edge weights
    init_deg<<<(N + 255) / 256, 256, 0, stream>>>(dinv, N);
    edgew_kernel<<<(E + 255) / 256, 256, 0, stream>>>(edge_attr, cols, aaaaa, w, dinv, E);
    dinv_kernel<<<(N + 255) / 256, 256, 0, stream>>>(dinv, N);

    const float* Ws[3]  = {W1, W2, W3};
    const float* bs[3]  = {b1, b2, b3};
    const float* wgs[3] = {wg1, wg2, wg3};
    const float* bgs[3] = {bg1, bg2, bg3};

    const float* cur = x;
    for (int l = 0; l < 3; l++) {
        // h = cur @ W
        gemm64<<<(N + 63) / 64, 256, 0, stream>>>(cur, Ws[l], bufB, N);
        // zero out-buffer (after gemm consumed bufA when cur==bufA; stream-ordered)
        hipMemsetAsync(bufA, 0, (size_t)N * HIDDEN * sizeof(float), stream);
        // scatter-add over edges
        {
            long long threads = (long long)E * 16;
            int blocks = (int)((threads + 255) / 256);
            scatter_kernel<<<blocks, 256, 0, stream>>>(bufB, rows, cols, w, dinv, bufA, E);
        }
        // self-loop + bias + relu
        {
            long long threads = (long long)N * 16;
            int blocks = (int)((threads + 255) / 256);
            finish_kernel<<<blocks, 256, 0, stream>>>(bufB, dinv, bs[l], bufA, N);
        }
        // attention pool into acc + l*68
        pool_kernel<<<1024, 256, 0, stream>>>(bufA, wgs[l], bgs[l], acc + l * 68, N);
        cur = bufA;
    }

    finalize_kernel<<<1, 192, 0, stream>>>(acc, out);
}

// Round 2
// 1140.181 us; speedup vs baseline: 3.3530x; 3.3530x over previous
//
#include <hip/hip_runtime.h>
#include <hip/hip_bf16.h>
#include <math.h>

#define HIDDEN    64
#define N_NODES   100000
#define N_EDGES   1250000
#define EDGE_FEAT 13

// ---------------- workspace layout (bytes) ----------------
#define OFF_W      0            // w       : E floats   (5,000,000)
#define OFF_DEG    5000000      // dinv    : N floats   (400,000)
#define OFF_CNT    5400000      // cnt     : N ints     (400,000)
#define OFF_START  5800000      // start   : N ints     (400,000)
#define OFF_CUR    6200000      // cursor  : N ints     (400,000)
#define OFF_PART   6600000      // partials: 128 ints   (512)
#define OFF_ACC    6601024      // acc     : 3*68 floats (816)
#define OFF_RPERM  6602048      // row_perm: E ints     (5,000,000)
#define OFF_NWPERM 11602048     // nw_perm : E floats   (5,000,000)
#define OFF_A      16602048     // bufA    : N*64 floats (25,600,000)
#define OFF_B      42202048     // bufB    : N*64 floats (25,600,000)
// total ~67.8 MB

#define SCAN_CHUNK 1024
#define SCAN_NB    ((N_NODES + SCAN_CHUNK - 1) / SCAN_CHUNK)   // 98

// deg[n] = 1.0 (self-loop weight)
__global__ void init_deg(float* __restrict__ deg, int n) {
    int i = blockIdx.x * blockDim.x + threadIdx.x;
    if (i < n) deg[i] = 1.0f;
}

// per-edge weight = edge_attr . softmax(aaaaa); atomic deg[col] += w; cnt[col]++
__global__ void edgew_kernel(const float* __restrict__ attr,
                             const int* __restrict__ cols,
                             const float* __restrict__ aaaaa,
                             float* __restrict__ w,
                             float* __restrict__ deg,
                             int* __restrict__ cnt, int E) {
    __shared__ float s[EDGE_FEAT];
    if (threadIdx.x == 0) {
        float m = -1e30f;
        for (int i = 0; i < EDGE_FEAT; i++) m = fmaxf(m, aaaaa[i]);
        float ex[EDGE_FEAT]; float sum = 0.f;
        for (int i = 0; i < EDGE_FEAT; i++) { ex[i] = __expf(aaaaa[i] - m); sum += ex[i]; }
        float inv = 1.f / sum;
        for (int i = 0; i < EDGE_FEAT; i++) s[i] = ex[i] * inv;
    }
    __syncthreads();
    int e = blockIdx.x * blockDim.x + threadIdx.x;
    if (e >= E) return;
    const float* a = attr + (size_t)e * EDGE_FEAT;
    float acc = 0.f;
#pragma unroll
    for (int f = 0; f < EDGE_FEAT; f++) acc = fmaf(a[f], s[f], acc);
    w[e] = acc;
    int c = cols[e];
    atomicAdd(&deg[c], acc);
    atomicAdd(&cnt[c], 1);
}

__global__ void dinv_kernel(float* __restrict__ deg, int n) {
    int i = blockIdx.x * blockDim.x + threadIdx.x;
    if (i < n) {
        float d = deg[i];
        deg[i] = (d > 0.f) ? rsqrtf(d) : 0.f;
    }
}

// ---- 3-kernel exclusive scan over cnt[N] -> start[N] (and cursor copy) ----
__global__ void scan1(const int* __restrict__ cnt, int* __restrict__ partial, int N) {
    __shared__ int s[256];
    int b = blockIdx.x, t = threadIdx.x;
    int base = b * SCAN_CHUNK + t * 4;
    int sum = 0;
#pragma unroll
    for (int i = 0; i < 4; i++) { int idx = base + i; if (idx < N) sum += cnt[idx]; }
    s[t] = sum; __syncthreads();
    for (int off = 128; off > 0; off >>= 1) {
        if (t < off) s[t] += s[t + off];
        __syncthreads();
    }
    if (t == 0) partial[b] = s[0];
}

__global__ void scan2(int* __restrict__ partial, int nb) {
    if (threadIdx.x == 0) {
        int run = 0;
        for (int i = 0; i < nb; i++) { int v = partial[i]; partial[i] = run; run += v; }
    }
}

__global__ void scan3(const int* __restrict__ cnt, const int* __restrict__ partial,
                      int* __restrict__ start, int* __restrict__ cursor, int N) {
    __shared__ int s[256];
    int b = blockIdx.x, t = threadIdx.x;
    int base = b * SCAN_CHUNK + t * 4;
    int v[4]; int sum = 0;
#pragma unroll
    for (int i = 0; i < 4; i++) { int idx = base + i; v[i] = (idx < N) ? cnt[idx] : 0; sum += v[i]; }
    s[t] = sum; __syncthreads();
    // Hillis-Steele inclusive scan over 256 thread sums
    for (int off = 1; off < 256; off <<= 1) {
        int x = (t >= off) ? s[t - off] : 0;
        __syncthreads();
        s[t] += x;
        __syncthreads();
    }
    int excl = (t == 0) ? 0 : s[t - 1];
    int off0 = partial[b] + excl;
#pragma unroll
    for (int i = 0; i < 4; i++) {
        int idx = base + i;
        if (idx < N) { start[idx] = off0; cursor[idx] = off0; off0 += v[i]; }
    }
}

// permute edges into destination-sorted order; precompute norm
__global__ void place_kernel(const int* __restrict__ rows, const int* __restrict__ cols,
                             const float* __restrict__ w, const float* __restrict__ dinv,
                             int* __restrict__ cursor,
                             int* __restrict__ row_perm, float* __restrict__ nw_perm, int E) {
    int e = blockIdx.x * blockDim.x + threadIdx.x;
    if (e >= E) return;
    int r = rows[e], c = cols[e];
    int slot = atomicAdd(&cursor[c], 1);
    row_perm[slot] = r;
    nw_perm[slot] = dinv[r] * w[e] * dinv[c];
}

// B[r,c] = sum_k A[r,k] * W[k,c]   (64x64 W staged in LDS; 64 rows/block)
__global__ __launch_bounds__(256) void gemm64(const float* __restrict__ A,
                                              const float* __restrict__ W,
                                              float* __restrict__ B, int N) {
    __shared__ float Ws[HIDDEN * HIDDEN];
    int tid = threadIdx.x;
    for (int i = tid; i < HIDDEN * HIDDEN; i += 256) Ws[i] = W[i];
    __syncthreads();
    int r = blockIdx.x * 64 + (tid >> 2);
    int c0 = (tid & 3) * 16;
    if (r >= N) return;
    const float* a = A + (size_t)r * HIDDEN;
    float acc[16];
#pragma unroll
    for (int j = 0; j < 16; j++) acc[j] = 0.f;
    for (int k = 0; k < HIDDEN; k++) {
        float av = a[k];
        const float* wrow = &Ws[k * HIDDEN + c0];
#pragma unroll
        for (int j = 0; j < 16; j++) acc[j] = fmaf(av, wrow[j], acc[j]);
    }
    float* b = B + (size_t)r * HIDDEN + c0;
#pragma unroll
    for (int j = 0; j < 16; j++) b[j] = acc[j];
}

// one wave per destination node: gather incoming rows of h, + self-loop + bias + relu
__global__ __launch_bounds__(256) void gather_kernel(
    const float* __restrict__ h,
    const int* __restrict__ start, const int* __restrict__ cnt,
    const int* __restrict__ row_perm, const float* __restrict__ nw_perm,
    const float* __restrict__ dinv, const float* __restrict__ bias,
    float* __restrict__ out, int N)
{
    int lane = threadIdx.x & 63;
    int n = blockIdx.x * 4 + (threadIdx.x >> 6);
    if (n >= N) return;
    float di = dinv[n];
    float acc = fmaf(di * di, h[(size_t)n * HIDDEN + lane], bias[lane]);
    int s = start[n], e = s + cnt[n];
    for (int k = s; k < e; k++) {
        int r = row_perm[k];
        float nw = nw_perm[k];
        acc = fmaf(nw, h[(size_t)r * HIDDEN + lane], acc);
    }
    out[(size_t)n * HIDDEN + lane] = fmaxf(acc, 0.f);
}

// attention pool: acc[0..63] += sum_n exp(sigmoid(x_n.wg+bg)) * x_n ; acc[64] += sum exp(...)
__global__ void pool_kernel(const float* __restrict__ x,
                            const float* __restrict__ wg,
                            const float* __restrict__ bg,
                            float* __restrict__ acc, int N) {
    int lane = threadIdx.x & 63;
    int wave = (int)(((long long)blockIdx.x * blockDim.x + threadIdx.x) >> 6);
    int nwaves = (gridDim.x * blockDim.x) >> 6;
    float wgv = wg[lane];
    float bg0 = bg[0];
    float accv = 0.f, accs = 0.f;
    for (int n = wave; n < N; n += nwaves) {
        float xv = x[(size_t)n * HIDDEN + lane];
        float p = xv * wgv;
#pragma unroll
        for (int m = 32; m > 0; m >>= 1) p += __shfl_xor(p, m, 64);
        float g = 1.f / (1.f + __expf(-(p + bg0)));
        float e = __expf(g);
        accv = fmaf(e, xv, accv);
        accs += e;
    }
    atomicAdd(&acc[lane], accv);
    if (lane == 0) atomicAdd(&acc[64], accs);  // e is lane-uniform; add once per wave
}

__global__ void finalize_kernel(const float* __restrict__ acc, float* __restrict__ out) {
    int i = threadIdx.x;  // 192 threads
    if (i >= 3 * HIDDEN) return;
    int layer = i >> 6, c = i & 63;
    const float* a = acc + layer * 68;
    out[i] = a[c] / a[64];
}

extern "C" void kernel_launch(void* const* d_in, const int* in_sizes, int n_in,
                              void* d_out, int out_size, void* d_ws, size_t ws_size,
                              hipStream_t stream) {
    const float* x          = (const float*)d_in[0];
    const int*   edge_index = (const int*)  d_in[1];   // [2,E] flat: rows then cols
    const float* edge_attr  = (const float*)d_in[2];
    const float* aaaaa      = (const float*)d_in[3];
    const float* W1 = (const float*)d_in[4];  const float* b1 = (const float*)d_in[5];
    const float* W2 = (const float*)d_in[6];  const float* b2 = (const float*)d_in[7];
    const float* W3 = (const float*)d_in[8];  const float* b3 = (const float*)d_in[9];
    const float* wg1 = (const float*)d_in[10]; const float* bg1 = (const float*)d_in[11];
    const float* wg2 = (const float*)d_in[12]; const float* bg2 = (const float*)d_in[13];
    const float* wg3 = (const float*)d_in[14]; const float* bg3 = (const float*)d_in[15];
    float* out = (float*)d_out;

    char* ws = (char*)d_ws;
    float* w        = (float*)(ws + OFF_W);
    float* dinv     = (float*)(ws + OFF_DEG);
    int*   cnt      = (int*)  (ws + OFF_CNT);
    int*   startA   = (int*)  (ws + OFF_START);
    int*   cursor   = (int*)  (ws + OFF_CUR);
    int*   partial  = (int*)  (ws + OFF_PART);
    float* acc      = (float*)(ws + OFF_ACC);
    int*   row_perm = (int*)  (ws + OFF_RPERM);
    float* nw_perm  = (float*)(ws + OFF_NWPERM);
    float* bufA     = (float*)(ws + OFF_A);
    float* bufB     = (float*)(ws + OFF_B);

    const int* rows = edge_index;
    const int* cols = edge_index + N_EDGES;
    const int N = N_NODES, E = N_EDGES;

    hipMemsetAsync(acc, 0, 3 * 68 * sizeof(float), stream);
    hipMemsetAsync(cnt, 0, N * sizeof(int), stream);

    init_deg<<<(N + 255) / 256, 256, 0, stream>>>(dinv, N);
    edgew_kernel<<<(E + 255) / 256, 256, 0, stream>>>(edge_attr, cols, aaaaa, w, dinv, cnt, E);
    dinv_kernel<<<(N + 255) / 256, 256, 0, stream>>>(dinv, N);

    // CSR build: scan counts -> start/cursor, then permute edges
    scan1<<<SCAN_NB, 256, 0, stream>>>(cnt, partial, N);
    scan2<<<1, 64, 0, stream>>>(partial, SCAN_NB);
    scan3<<<SCAN_NB, 256, 0, stream>>>(cnt, partial, startA, cursor, N);
    place_kernel<<<(E + 255) / 256, 256, 0, stream>>>(rows, cols, w, dinv, cursor,
                                                      row_perm, nw_perm, E);

    const float* Wm[3]  = {W1, W2, W3};
    const float* bs[3]  = {b1, b2, b3};
    const float* wgs[3] = {wg1, wg2, wg3};
    const float* bgs[3] = {bg1, bg2, bg3};

    const float* cur = x;
    for (int l = 0; l < 3; l++) {
        gemm64<<<(N + 63) / 64, 256, 0, stream>>>(cur, Wm[l], bufB, N);
        gather_kernel<<<(N + 3) / 4, 256, 0, stream>>>(bufB, startA, cnt, row_perm, nw_perm,
                                                       dinv, bs[l], bufA, N);
        pool_kernel<<<1024, 256, 0, stream>>>(bufA, wgs[l], bgs[l], acc + l * 68, N);
        cur = bufA;
    }

    finalize_kernel<<<1, 192, 0, stream>>>(acc, out);
}

// Round 3
// 574.148 us; speedup vs baseline: 6.6585x; 1.9859x over previous
//
#include <hip/hip_runtime.h>
#include <hip/hip_bf16.h>
#include <math.h>

#define HIDDEN    64
#define N_NODES   100000
#define N_EDGES   1250000
#define EDGE_FEAT 13

#define GATHER_BLOCKS 2048          // 8192 waves = 32 waves/CU on 256 CUs

// ---------------- workspace layout (bytes) ----------------
#define OFF_DEG    0                // dinv : N floats            (400,000)
#define OFF_CNT    400000           // cnt  : N ints              (400,000)
#define OFF_START  800000           // start: N ints              (400,000)
#define OFF_CUR    1200000          // cursor (=end after place)  (400,000)
#define OFF_PART   1600000          // scan partials: 128 ints    (512)
#define OFF_ACC    1600512          // acc  : 3*65 floats         (780 -> pad 1024)
#define OFF_POOLP  1601536          // poolpart: 3*65*2048 floats (1,597,440)
#define OFF_REC    3198976          // edge_rec: E int2           (10,000,000)
#define OFF_A      13198976         // bufA : N*64 floats         (25,600,000)
#define OFF_B      38798976         // bufB : N*64 floats         (25,600,000)
// w[] (E floats, 5 MB) aliases the start of bufB: dead before first gemm writes bufB.
// total = 64.4 MB (<= round-2's proven 67.8 MB)

__global__ void init_deg(float* __restrict__ deg, int n) {
    int i = blockIdx.x * blockDim.x + threadIdx.x;
    if (i < n) deg[i] = 1.0f;
}

// per-edge weight = edge_attr . softmax(aaaaa); atomic deg[col] += w; cnt[col]++
__global__ void edgew_kernel(const float* __restrict__ attr,
                             const int* __restrict__ cols,
                             const float* __restrict__ aaaaa,
                             float* __restrict__ w,
                             float* __restrict__ deg,
                             int* __restrict__ cnt, int E) {
    __shared__ float s[EDGE_FEAT];
    if (threadIdx.x == 0) {
        float m = -1e30f;
        for (int i = 0; i < EDGE_FEAT; i++) m = fmaxf(m, aaaaa[i]);
        float ex[EDGE_FEAT]; float sum = 0.f;
        for (int i = 0; i < EDGE_FEAT; i++) { ex[i] = __expf(aaaaa[i] - m); sum += ex[i]; }
        float inv = 1.f / sum;
        for (int i = 0; i < EDGE_FEAT; i++) s[i] = ex[i] * inv;
    }
    __syncthreads();
    int e = blockIdx.x * blockDim.x + threadIdx.x;
    if (e >= E) return;
    const float* a = attr + (size_t)e * EDGE_FEAT;
    float acc = 0.f;
#pragma unroll
    for (int f = 0; f < EDGE_FEAT; f++) acc = fmaf(a[f], s[f], acc);
    w[e] = acc;
    int c = cols[e];
    atomicAdd(&deg[c], acc);
    atomicAdd(&cnt[c], 1);
}

__global__ void dinv_kernel(float* __restrict__ deg, int n) {
    int i = blockIdx.x * blockDim.x + threadIdx.x;
    if (i < n) {
        float d = deg[i];
        deg[i] = (d > 0.f) ? rsqrtf(d) : 0.f;
    }
}

// ---- 3-kernel exclusive scan over cnt[N] -> start[N] + cursor copy ----
#define SCAN_CHUNK 1024
#define SCAN_NB    ((N_NODES + SCAN_CHUNK - 1) / SCAN_CHUNK)   // 98

__global__ void scan1(const int* __restrict__ cnt, int* __restrict__ partial, int N) {
    __shared__ int s[256];
    int b = blockIdx.x, t = threadIdx.x;
    int base = b * SCAN_CHUNK + t * 4;
    int sum = 0;
#pragma unroll
    for (int i = 0; i < 4; i++) { int idx = base + i; if (idx < N) sum += cnt[idx]; }
    s[t] = sum; __syncthreads();
    for (int off = 128; off > 0; off >>= 1) {
        if (t < off) s[t] += s[t + off];
        __syncthreads();
    }
    if (t == 0) partial[b] = s[0];
}

// one-wave exclusive scan over <=128 partials
__global__ void scan2(int* __restrict__ partial, int nb) {
    int lane = threadIdx.x;   // 64 threads
    int v0 = (lane < nb) ? partial[lane] : 0;
    int v1 = (lane + 64 < nb) ? partial[lane + 64] : 0;
    int s0 = v0;
#pragma unroll
    for (int m = 1; m < 64; m <<= 1) { int t = __shfl_up(s0, m, 64); if (lane >= m) s0 += t; }
    int total0 = __shfl(s0, 63, 64);
    int s1 = v1;
#pragma unroll
    for (int m = 1; m < 64; m <<= 1) { int t = __shfl_up(s1, m, 64); if (lane >= m) s1 += t; }
    if (lane < nb) partial[lane] = s0 - v0;
    if (lane + 64 < nb) partial[lane + 64] = total0 + s1 - v1;
}

__global__ void scan3(const int* __restrict__ cnt, const int* __restrict__ partial,
                      int* __restrict__ start, int* __restrict__ cursor, int N) {
    __shared__ int s[256];
    int b = blockIdx.x, t = threadIdx.x;
    int base = b * SCAN_CHUNK + t * 4;
    int v[4]; int sum = 0;
#pragma unroll
    for (int i = 0; i < 4; i++) { int idx = base + i; v[i] = (idx < N) ? cnt[idx] : 0; sum += v[i]; }
    s[t] = sum; __syncthreads();
    for (int off = 1; off < 256; off <<= 1) {
        int x = (t >= off) ? s[t - off] : 0;
        __syncthreads();
        s[t] += x;
        __syncthreads();
    }
    int excl = (t == 0) ? 0 : s[t - 1];
    int off0 = partial[b] + excl;
#pragma unroll
    for (int i = 0; i < 4; i++) {
        int idx = base + i;
        if (idx < N) { start[idx] = off0; cursor[idx] = off0; off0 += v[i]; }
    }
}

// permute edges into destination-sorted order; one 8B record per edge
__global__ void place_kernel(const int* __restrict__ rows, const int* __restrict__ cols,
                             const float* __restrict__ w, const float* __restrict__ dinv,
                             int* __restrict__ cursor, int2* __restrict__ rec, int E) {
    int e = blockIdx.x * blockDim.x + threadIdx.x;
    if (e >= E) return;
    int r = rows[e], c = cols[e];
    int slot = atomicAdd(&cursor[c], 1);
    float nw = dinv[r] * w[e] * dinv[c];
    rec[slot] = make_int2(r, __float_as_int(nw));
}

// B = A @ W : 256 rows/block, 4 rows x 16 cols per thread, W staged in LDS
__global__ __launch_bounds__(256) void gemm64(const float* __restrict__ A,
                                              const float* __restrict__ W,
                                              float* __restrict__ B, int N) {
    __shared__ float Ws[HIDDEN * HIDDEN];
    int tid = threadIdx.x;
    {
        const float4* Wv = (const float4*)W;
        float4* Sv = (float4*)Ws;
#pragma unroll
        for (int i = 0; i < 4; i++) Sv[tid + 256 * i] = Wv[tid + 256 * i];
    }
    __syncthreads();
    int rg = tid >> 2;                 // 0..63
    int c0 = (tid & 3) * 16;
    int rbase = blockIdx.x * 256 + rg; // rows: rbase + 64*i
    int rld[4];
    bool rok[4];
#pragma unroll
    for (int i = 0; i < 4; i++) {
        int r = rbase + 64 * i;
        rok[i] = (r < N);
        rld[i] = rok[i] ? r : 0;
    }
    float acc[4][16];
#pragma unroll
    for (int i = 0; i < 4; i++)
#pragma unroll
        for (int j = 0; j < 16; j++) acc[i][j] = 0.f;

    for (int k = 0; k < HIDDEN; k += 4) {
        float4 a4[4];
#pragma unroll
        for (int i = 0; i < 4; i++)
            a4[i] = *(const float4*)(A + (size_t)rld[i] * HIDDEN + k);
#pragma unroll
        for (int kk = 0; kk < 4; kk++) {
            const float* wr = &Ws[(k + kk) * HIDDEN + c0];
            float4 W0 = *(const float4*)(wr);
            float4 W1 = *(const float4*)(wr + 4);
            float4 W2 = *(const float4*)(wr + 8);
            float4 W3 = *(const float4*)(wr + 12);
            float wv[16] = {W0.x, W0.y, W0.z, W0.w, W1.x, W1.y, W1.z, W1.w,
                            W2.x, W2.y, W2.z, W2.w, W3.x, W3.y, W3.z, W3.w};
#pragma unroll
            for (int i = 0; i < 4; i++) {
                float ak[4] = {a4[i].x, a4[i].y, a4[i].z, a4[i].w};
                float av = ak[kk];
#pragma unroll
                for (int j = 0; j < 16; j++) acc[i][j] = fmaf(av, wv[j], acc[i][j]);
            }
        }
    }
#pragma unroll
    for (int i = 0; i < 4; i++) {
        if (!rok[i]) continue;
        float* b = B + (size_t)(rbase + 64 * i) * HIDDEN + c0;
#pragma unroll
        for (int j = 0; j < 4; j++)
            *(float4*)(b + 4 * j) = make_float4(acc[i][4*j], acc[i][4*j+1],
                                                acc[i][4*j+2], acc[i][4*j+3]);
    }
}

// one wave per node (grid-stride): gather + self-loop + bias + relu + fused attention pool
__global__ __launch_bounds__(256) void gather_pool_kernel(
    const float* __restrict__ h,
    const int* __restrict__ start, const int* __restrict__ endp,
    const int2* __restrict__ rec,
    const float* __restrict__ dinv, const float* __restrict__ bias,
    const float* __restrict__ wg, const float* __restrict__ bg,
    float* __restrict__ out, float* __restrict__ poolpart, int N)
{
    __shared__ float sred[4][65];
    int lane = threadIdx.x & 63;
    int wid  = threadIdx.x >> 6;
    int wave = blockIdx.x * 4 + wid;
    const int nwaves = GATHER_BLOCKS * 4;
    float wgv = wg[lane];
    float bg0 = bg[0];
    float bv  = bias[lane];
    float accv = 0.f, accs = 0.f;

    for (int n = wave; n < N; n += nwaves) {
        float di = dinv[n];
        float a0 = fmaf(di * di, h[(size_t)n * HIDDEN + lane], bv);
        float a1 = 0.f, a2 = 0.f, a3 = 0.f;
        int s = start[n], e = endp[n];
        int k = s;
        for (; k + 4 <= e; k += 4) {
            int2 r0 = rec[k], r1 = rec[k + 1], r2 = rec[k + 2], r3 = rec[k + 3];
            float h0 = h[(size_t)r0.x * HIDDEN + lane];
            float h1 = h[(size_t)r1.x * HIDDEN + lane];
            float h2 = h[(size_t)r2.x * HIDDEN + lane];
            float h3 = h[(size_t)r3.x * HIDDEN + lane];
            a0 = fmaf(__int_as_float(r0.y), h0, a0);
            a1 = fmaf(__int_as_float(r1.y), h1, a1);
            a2 = fmaf(__int_as_float(r2.y), h2, a2);
            a3 = fmaf(__int_as_float(r3.y), h3, a3);
        }
        for (; k < e; k++) {
            int2 r = rec[k];
            a0 = fmaf(__int_as_float(r.y), h[(size_t)r.x * HIDDEN + lane], a0);
        }
        float v = fmaxf((a0 + a1) + (a2 + a3), 0.f);
        out[(size_t)n * HIDDEN + lane] = v;
        // attention-pool contribution
        float p = v * wgv;
#pragma unroll
        for (int m = 32; m > 0; m >>= 1) p += __shfl_xor(p, m, 64);
        float g = 1.f / (1.f + __expf(-(p + bg0)));
        float eg = __expf(g);
        accv = fmaf(eg, v, accv);
        accs += eg;
    }

    sred[wid][lane] = accv;
    if (lane == 0) sred[wid][64] = accs;
    __syncthreads();
    if (wid == 0) {
        float s0 = sred[0][lane] + sred[1][lane] + sred[2][lane] + sred[3][lane];
        poolpart[(size_t)lane * GATHER_BLOCKS + blockIdx.x] = s0;
        if (lane == 0) {
            float ss = sred[0][64] + sred[1][64] + sred[2][64] + sred[3][64];
            poolpart[(size_t)64 * GATHER_BLOCKS + blockIdx.x] = ss;
        }
    }
}

// one wave per (layer, entry): sum 2048 block partials -> acc[3*65]
__global__ void pool_reduce(const float* __restrict__ poolpart, float* __restrict__ acc) {
    int entry = (int)((blockIdx.x * blockDim.x + threadIdx.x) >> 6);  // 0..194
    int lane = threadIdx.x & 63;
    if (entry >= 3 * 65) return;
    const float* p = poolpart + (size_t)entry * GATHER_BLOCKS;
    float s = 0.f;
    for (int i = lane; i < GATHER_BLOCKS; i += 64) s += p[i];
#pragma unroll
    for (int m = 32; m > 0; m >>= 1) s += __shfl_xor(s, m, 64);
    if (lane == 0) acc[entry] = s;
}

__global__ void finalize_kernel(const float* __restrict__ acc, float* __restrict__ out) {
    int i = threadIdx.x;  // 192 threads
    if (i >= 3 * HIDDEN) return;
    int layer = i >> 6, c = i & 63;
    const float* a = acc + layer * 65;
    out[i] = a[c] / a[64];
}

extern "C" void kernel_launch(void* const* d_in, const int* in_sizes, int n_in,
                              void* d_out, int out_size, void* d_ws, size_t ws_size,
                              hipStream_t stream) {
    const float* x          = (const float*)d_in[0];
    const int*   edge_index = (const int*)  d_in[1];   // [2,E] flat: rows then cols
    const float* edge_attr  = (const float*)d_in[2];
    const float* aaaaa      = (const float*)d_in[3];
    const float* W1 = (const float*)d_in[4];  const float* b1 = (const float*)d_in[5];
    const float* W2 = (const float*)d_in[6];  const float* b2 = (const float*)d_in[7];
    const float* W3 = (const float*)d_in[8];  const float* b3 = (const float*)d_in[9];
    const float* wg1 = (const float*)d_in[10]; const float* bg1 = (const float*)d_in[11];
    const float* wg2 = (const float*)d_in[12]; const float* bg2 = (const float*)d_in[13];
    const float* wg3 = (const float*)d_in[14]; const float* bg3 = (const float*)d_in[15];
    float* out = (float*)d_out;

    char* ws = (char*)d_ws;
    float* dinv     = (float*)(ws + OFF_DEG);
    int*   cnt      = (int*)  (ws + OFF_CNT);
    int*   startA   = (int*)  (ws + OFF_START);
    int*   cursor   = (int*)  (ws + OFF_CUR);
    int*   spartial = (int*)  (ws + OFF_PART);
    float* acc      = (float*)(ws + OFF_ACC);
    float* poolpart = (float*)(ws + OFF_POOLP);
    int2*  rec      = (int2*) (ws + OFF_REC);
    float* bufA     = (float*)(ws + OFF_A);
    float* bufB     = (float*)(ws + OFF_B);
    float* w        = bufB;   // alias: dead before first gemm writes bufB

    const int* rows = edge_index;
    const int* cols = edge_index + N_EDGES;
    const int N = N_NODES, E = N_EDGES;

    hipMemsetAsync(cnt, 0, N * sizeof(int), stream);
    init_deg<<<(N + 255) / 256, 256, 0, stream>>>(dinv, N);
    edgew_kernel<<<(E + 255) / 256, 256, 0, stream>>>(edge_attr, cols, aaaaa, w, dinv, cnt, E);
    dinv_kernel<<<(N + 255) / 256, 256, 0, stream>>>(dinv, N);

    scan1<<<SCAN_NB, 256, 0, stream>>>(cnt, spartial, N);
    scan2<<<1, 64, 0, stream>>>(spartial, SCAN_NB);
    scan3<<<SCAN_NB, 256, 0, stream>>>(cnt, spartial, startA, cursor, N);
    place_kernel<<<(E + 255) / 256, 256, 0, stream>>>(rows, cols, w, dinv, cursor, rec, E);
    // after place: cursor[n] == end offset of node n

    const float* Wm[3]  = {W1, W2, W3};
    const float* bs[3]  = {b1, b2, b3};
    const float* wgs[3] = {wg1, wg2, wg3};
    const float* bgs[3] = {bg1, bg2, bg3};

    const float* cur = x;
    for (int l = 0; l < 3; l++) {
        gemm64<<<(N + 255) / 256, 256, 0, stream>>>(cur, Wm[l], bufB, N);
        gather_pool_kernel<<<GATHER_BLOCKS, 256, 0, stream>>>(
            bufB, startA, cursor, rec, dinv, bs[l], wgs[l], bgs[l],
            bufA, poolpart + (size_t)l * 65 * GATHER_BLOCKS, N);
        cur = bufA;
    }

    pool_reduce<<<(3 * 65 * 64 + 255) / 256, 256, 0, stream>>>(poolpart, acc);
    finalize_kernel<<<1, 192, 0, stream>>>(acc, out);
}

// Round 4
// 554.144 us; speedup vs baseline: 6.8989x; 1.0361x over previous
//
#include <hip/hip_runtime.h>
#include <hip/hip_bf16.h>
#include <math.h>

#define HIDDEN    64
#define N_NODES   100000
#define N_EDGES   1250000
#define EDGE_FEAT 13

#define GATHER_BLOCKS 2048          // 8192 waves

typedef unsigned short bf16_t;
typedef unsigned long long u64;

static __device__ __forceinline__ float bf2f(bf16_t u) {
    union { unsigned int i; float f; } x; x.i = ((unsigned int)u) << 16; return x.f;
}
static __device__ __forceinline__ bf16_t f2bf(float f) {
    union { float f; unsigned int i; } u; u.f = f;
    unsigned int r = u.i + 0x7FFFu + ((u.i >> 16) & 1u);   // RNE
    return (bf16_t)(r >> 16);
}

// ---------------- workspace layout (bytes) ----------------
#define OFF_PK     0                // pk   : N u64 (packed cnt|deg) (800,000)
#define OFF_DEG    800000           // dinv : N floats            (400,000)
#define OFF_CNT    1200000          // cnt  : N ints              (400,000)
#define OFF_START  1600000          // start: N ints              (400,000)
#define OFF_CUR    2000000          // cursor (=end after place)  (400,000)
#define OFF_PART   2400000          // scan partials: 128 ints    (512)
#define OFF_ACC    2400512          // acc  : 3*65 floats         (pad 1024)
#define OFF_POOLP  2401536          // poolpart: 3*65*2048 floats (1,597,440)
#define OFF_REC    3998976          // edge_rec: E int2           (10,000,000)
#define OFF_A      13998976         // bufA : N*64 bf16           (12,800,000)
#define OFF_B      26798976         // bufB : N*64 bf16           (12,800,000)
#define OFF_WTMP   39598976         // w    : E floats            (5,000,000)
// total = 44.6 MB

// per-edge weight = edge_attr . softmax(aaaaa), fully coalesced via LDS transpose;
// one packed u64 atomic per edge: pk[col] += (1<<40) + round(w * 2^20)
__global__ __launch_bounds__(256) void edgew_kernel(
    const float* __restrict__ attr, const int* __restrict__ cols,
    const float* __restrict__ aaaaa, float* __restrict__ w,
    u64* __restrict__ pk, int E)
{
    __shared__ float lds[EDGE_FEAT * 256];
    __shared__ float s[16];
    int t = threadIdx.x;
    if (t == 0) {
        float m = -1e30f;
        for (int i = 0; i < EDGE_FEAT; i++) m = fmaxf(m, aaaaa[i]);
        float ex[EDGE_FEAT]; float sum = 0.f;
        for (int i = 0; i < EDGE_FEAT; i++) { ex[i] = __expf(aaaaa[i] - m); sum += ex[i]; }
        float inv = 1.f / sum;
        for (int i = 0; i < EDGE_FEAT; i++) s[i] = ex[i] * inv;
    }
    int base_e = blockIdx.x * 256;
    size_t base = (size_t)base_e * EDGE_FEAT;
    int limit = (min(256, E - base_e)) * EDGE_FEAT;
#pragma unroll
    for (int j = 0; j < EDGE_FEAT; j++) {
        int idx = t + j * 256;
        if (idx < limit) lds[idx] = attr[base + idx];
    }
    __syncthreads();
    int e = base_e + t;
    if (e >= E) return;
    float acc = 0.f;
    const float* row = &lds[t * EDGE_FEAT];
#pragma unroll
    for (int f = 0; f < EDGE_FEAT; f++) acc = fmaf(row[f], s[f], acc);
    w[e] = acc;
    int c = cols[e];
    u64 q = (u64)(fmaxf(acc, 0.f) * 1048576.0f + 0.5f);
    atomicAdd(&pk[c], (1ULL << 40) + q);
}

// unpack: cnt[n] = pk>>40 ; dinv[n] = rsqrt(1 + fixedpoint(deg))
__global__ void prep_kernel(const u64* __restrict__ pk, int* __restrict__ cnt,
                            float* __restrict__ dinv, int n) {
    int i = blockIdx.x * blockDim.x + threadIdx.x;
    if (i >= n) return;
    u64 p = pk[i];
    cnt[i] = (int)(p >> 40);
    float deg = 1.0f + (float)(p & ((1ULL << 40) - 1)) * (1.0f / 1048576.0f);
    dinv[i] = rsqrtf(deg);
}

// ---- 3-kernel exclusive scan over cnt[N] -> start[N] + cursor copy ----
#define SCAN_CHUNK 1024
#define SCAN_NB    ((N_NODES + SCAN_CHUNK - 1) / SCAN_CHUNK)   // 98

__global__ void scan1(const int* __restrict__ cnt, int* __restrict__ partial, int N) {
    __shared__ int s[256];
    int b = blockIdx.x, t = threadIdx.x;
    int base = b * SCAN_CHUNK + t * 4;
    int sum = 0;
#pragma unroll
    for (int i = 0; i < 4; i++) { int idx = base + i; if (idx < N) sum += cnt[idx]; }
    s[t] = sum; __syncthreads();
    for (int off = 128; off > 0; off >>= 1) {
        if (t < off) s[t] += s[t + off];
        __syncthreads();
    }
    if (t == 0) partial[b] = s[0];
}

__global__ void scan2(int* __restrict__ partial, int nb) {
    int lane = threadIdx.x;   // 64 threads
    int v0 = (lane < nb) ? partial[lane] : 0;
    int v1 = (lane + 64 < nb) ? partial[lane + 64] : 0;
    int s0 = v0;
#pragma unroll
    for (int m = 1; m < 64; m <<= 1) { int t = __shfl_up(s0, m, 64); if (lane >= m) s0 += t; }
    int total0 = __shfl(s0, 63, 64);
    int s1 = v1;
#pragma unroll
    for (int m = 1; m < 64; m <<= 1) { int t = __shfl_up(s1, m, 64); if (lane >= m) s1 += t; }
    if (lane < nb) partial[lane] = s0 - v0;
    if (lane + 64 < nb) partial[lane + 64] = total0 + s1 - v1;
}

__global__ void scan3(const int* __restrict__ cnt, const int* __restrict__ partial,
                      int* __restrict__ start, int* __restrict__ cursor, int N) {
    __shared__ int s[256];
    int b = blockIdx.x, t = threadIdx.x;
    int base = b * SCAN_CHUNK + t * 4;
    int v[4]; int sum = 0;
#pragma unroll
    for (int i = 0; i < 4; i++) { int idx = base + i; v[i] = (idx < N) ? cnt[idx] : 0; sum += v[i]; }
    s[t] = sum; __syncthreads();
    for (int off = 1; off < 256; off <<= 1) {
        int x = (t >= off) ? s[t - off] : 0;
        __syncthreads();
        s[t] += x;
        __syncthreads();
    }
    int excl = (t == 0) ? 0 : s[t - 1];
    int off0 = partial[b] + excl;
#pragma unroll
    for (int i = 0; i < 4; i++) {
        int idx = base + i;
        if (idx < N) { start[idx] = off0; cursor[idx] = off0; off0 += v[i]; }
    }
}

// permute edges into destination-sorted order; one 8B record per edge
__global__ void place_kernel(const int* __restrict__ rows, const int* __restrict__ cols,
                             const float* __restrict__ w, const float* __restrict__ dinv,
                             int* __restrict__ cursor, int2* __restrict__ rec, int E) {
    int e = blockIdx.x * blockDim.x + threadIdx.x;
    if (e >= E) return;
    int r = rows[e], c = cols[e];
    int slot = atomicAdd(&cursor[c], 1);
    float nw = dinv[r] * w[e] * dinv[c];
    rec[slot] = make_int2(r, __float_as_int(nw));
}

// ---- feature-type abstraction for gemm input ----
template <typename T> struct Feat;
template <> struct Feat<float> {
    static __device__ __forceinline__ float4 ld4(const float* A, size_t off) {
        return *(const float4*)(A + off);
    }
};
template <> struct Feat<bf16_t> {
    static __device__ __forceinline__ float4 ld4(const bf16_t* A, size_t off) {
        uint2 v = *(const uint2*)(A + off);
        float4 r;
        r.x = bf2f((bf16_t)(v.x & 0xffffu));
        r.y = bf2f((bf16_t)(v.x >> 16));
        r.z = bf2f((bf16_t)(v.y & 0xffffu));
        r.w = bf2f((bf16_t)(v.y >> 16));
        return r;
    }
};

// B = A @ W : 256 rows/block, 4 rows x 16 cols per thread, W staged in LDS; B in bf16
template <typename TIn>
__global__ __launch_bounds__(256) void gemm64(const TIn* __restrict__ A,
                                              const float* __restrict__ W,
                                              bf16_t* __restrict__ B, int N) {
    __shared__ float Ws[HIDDEN * HIDDEN];
    int tid = threadIdx.x;
    {
        const float4* Wv = (const float4*)W;
        float4* Sv = (float4*)Ws;
#pragma unroll
        for (int i = 0; i < 4; i++) Sv[tid + 256 * i] = Wv[tid + 256 * i];
    }
    __syncthreads();
    int rg = tid >> 2;                 // 0..63
    int c0 = (tid & 3) * 16;
    int rbase = blockIdx.x * 256 + rg; // rows: rbase + 64*i
    int rld[4];
    bool rok[4];
#pragma unroll
    for (int i = 0; i < 4; i++) {
        int r = rbase + 64 * i;
        rok[i] = (r < N);
        rld[i] = rok[i] ? r : 0;
    }
    float acc[4][16];
#pragma unroll
    for (int i = 0; i < 4; i++)
#pragma unroll
        for (int j = 0; j < 16; j++) acc[i][j] = 0.f;

    for (int k = 0; k < HIDDEN; k += 4) {
        float4 a4[4];
#pragma unroll
        for (int i = 0; i < 4; i++)
            a4[i] = Feat<TIn>::ld4(A, (size_t)rld[i] * HIDDEN + k);
#pragma unroll
        for (int kk = 0; kk < 4; kk++) {
            const float* wr = &Ws[(k + kk) * HIDDEN + c0];
            float4 W0 = *(const float4*)(wr);
            float4 W1 = *(const float4*)(wr + 4);
            float4 W2 = *(const float4*)(wr + 8);
            float4 W3 = *(const float4*)(wr + 12);
            float wv[16] = {W0.x, W0.y, W0.z, W0.w, W1.x, W1.y, W1.z, W1.w,
                            W2.x, W2.y, W2.z, W2.w, W3.x, W3.y, W3.z, W3.w};
#pragma unroll
            for (int i = 0; i < 4; i++) {
                float ak[4] = {a4[i].x, a4[i].y, a4[i].z, a4[i].w};
                float av = ak[kk];
#pragma unroll
                for (int j = 0; j < 16; j++) acc[i][j] = fmaf(av, wv[j], acc[i][j]);
            }
        }
    }
#pragma unroll
    for (int i = 0; i < 4; i++) {
        if (!rok[i]) continue;
        bf16_t* b = B + (size_t)(rbase + 64 * i) * HIDDEN + c0;
        unsigned int p[8];
#pragma unroll
        for (int j = 0; j < 8; j++)
            p[j] = (unsigned int)f2bf(acc[i][2*j]) | ((unsigned int)f2bf(acc[i][2*j+1]) << 16);
        *(uint4*)(b)     = make_uint4(p[0], p[1], p[2], p[3]);
        *(uint4*)(b + 8) = make_uint4(p[4], p[5], p[6], p[7]);
    }
}

// one wave per node (grid-stride): gather + self-loop + bias + relu + fused attention pool
__global__ __launch_bounds__(256) void gather_pool_kernel(
    const bf16_t* __restrict__ h,
    const int* __restrict__ start, const int* __restrict__ endp,
    const int2* __restrict__ rec,
    const float* __restrict__ dinv, const float* __restrict__ bias,
    const float* __restrict__ wg, const float* __restrict__ bg,
    bf16_t* __restrict__ out, float* __restrict__ poolpart, int N)
{
    __shared__ float sred[4][65];
    int lane = threadIdx.x & 63;
    int wid  = threadIdx.x >> 6;
    int wave = blockIdx.x * 4 + wid;
    const int nwaves = GATHER_BLOCKS * 4;
    float wgv = wg[lane];
    float bg0 = bg[0];
    float bv  = bias[lane];
    float accv = 0.f, accs = 0.f;

    for (int n = wave; n < N; n += nwaves) {
        float di = dinv[n];
        float a0 = fmaf(di * di, bf2f(h[(size_t)n * HIDDEN + lane]), bv);
        float a1 = 0.f, a2 = 0.f, a3 = 0.f;
        int s = start[n], e = endp[n];
        int k = s;
        for (; k + 8 <= e; k += 8) {
            int2 r[8];
#pragma unroll
            for (int j = 0; j < 8; j++) r[j] = rec[k + j];
            float hv[8];
#pragma unroll
            for (int j = 0; j < 8; j++) hv[j] = bf2f(h[(size_t)r[j].x * HIDDEN + lane]);
            a0 = fmaf(__int_as_float(r[0].y), hv[0], a0);
            a1 = fmaf(__int_as_float(r[1].y), hv[1], a1);
            a2 = fmaf(__int_as_float(r[2].y), hv[2], a2);
            a3 = fmaf(__int_as_float(r[3].y), hv[3], a3);
            a0 = fmaf(__int_as_float(r[4].y), hv[4], a0);
            a1 = fmaf(__int_as_float(r[5].y), hv[5], a1);
            a2 = fmaf(__int_as_float(r[6].y), hv[6], a2);
            a3 = fmaf(__int_as_float(r[7].y), hv[7], a3);
        }
        for (; k < e; k++) {
            int2 r = rec[k];
            a0 = fmaf(__int_as_float(r.y), bf2f(h[(size_t)r.x * HIDDEN + lane]), a0);
        }
        float v = fmaxf((a0 + a1) + (a2 + a3), 0.f);
        out[(size_t)n * HIDDEN + lane] = f2bf(v);
        // attention-pool contribution (fp32 v, pre-quantization)
        float p = v * wgv;
#pragma unroll
        for (int m = 32; m > 0; m >>= 1) p += __shfl_xor(p, m, 64);
        float g = 1.f / (1.f + __expf(-(p + bg0)));
        float eg = __expf(g);
        accv = fmaf(eg, v, accv);
        accs += eg;
    }

    sred[wid][lane] = accv;
    if (lane == 0) sred[wid][64] = accs;
    __syncthreads();
    if (wid == 0) {
        float s0 = sred[0][lane] + sred[1][lane] + sred[2][lane] + sred[3][lane];
        poolpart[(size_t)lane * GATHER_BLOCKS + blockIdx.x] = s0;
        if (lane == 0) {
            float ss = sred[0][64] + sred[1][64] + sred[2][64] + sred[3][64];
            poolpart[(size_t)64 * GATHER_BLOCKS + blockIdx.x] = ss;
        }
    }
}

// one wave per (layer, entry): sum 2048 block partials -> acc[3*65]
__global__ void pool_reduce(const float* __restrict__ poolpart, float* __restrict__ acc) {
    int entry = (int)((blockIdx.x * blockDim.x + threadIdx.x) >> 6);  // 0..194
    int lane = threadIdx.x & 63;
    if (entry >= 3 * 65) return;
    const float* p = poolpart + (size_t)entry * GATHER_BLOCKS;
    float s = 0.f;
    for (int i = lane; i < GATHER_BLOCKS; i += 64) s += p[i];
#pragma unroll
    for (int m = 32; m > 0; m >>= 1) s += __shfl_xor(s, m, 64);
    if (lane == 0) acc[entry] = s;
}

__global__ void finalize_kernel(const float* __restrict__ acc, float* __restrict__ out) {
    int i = threadIdx.x;  // 192 threads
    if (i >= 3 * HIDDEN) return;
    int layer = i >> 6, c = i & 63;
    const float* a = acc + layer * 65;
    out[i] = a[c] / a[64];
}

extern "C" void kernel_launch(void* const* d_in, const int* in_sizes, int n_in,
                              void* d_out, int out_size, void* d_ws, size_t ws_size,
                              hipStream_t stream) {
    const float* x          = (const float*)d_in[0];
    const int*   edge_index = (const int*)  d_in[1];   // [2,E] flat: rows then cols
    const float* edge_attr  = (const float*)d_in[2];
    const float* aaaaa      = (const float*)d_in[3];
    const float* W1 = (const float*)d_in[4];  const float* b1 = (const float*)d_in[5];
    const float* W2 = (const float*)d_in[6];  const float* b2 = (const float*)d_in[7];
    const float* W3 = (const float*)d_in[8];  const float* b3 = (const float*)d_in[9];
    const float* wg1 = (const float*)d_in[10]; const float* bg1 = (const float*)d_in[11];
    const float* wg2 = (const float*)d_in[12]; const float* bg2 = (const float*)d_in[13];
    const float* wg3 = (const float*)d_in[14]; const float* bg3 = (const float*)d_in[15];
    float* out = (float*)d_out;

    char* ws = (char*)d_ws;
    u64*   pk       = (u64*)  (ws + OFF_PK);
    float* dinv     = (float*)(ws + OFF_DEG);
    int*   cnt      = (int*)  (ws + OFF_CNT);
    int*   startA   = (int*)  (ws + OFF_START);
    int*   cursor   = (int*)  (ws + OFF_CUR);
    int*   spartial = (int*)  (ws + OFF_PART);
    float* acc      = (float*)(ws + OFF_ACC);
    float* poolpart = (float*)(ws + OFF_POOLP);
    int2*  rec      = (int2*) (ws + OFF_REC);
    bf16_t* bufA    = (bf16_t*)(ws + OFF_A);
    bf16_t* bufB    = (bf16_t*)(ws + OFF_B);
    float* w        = (float*)(ws + OFF_WTMP);

    const int* rows = edge_index;
    const int* cols = edge_index + N_EDGES;
    const int N = N_NODES, E = N_EDGES;

    hipMemsetAsync(pk, 0, N * sizeof(u64), stream);
    edgew_kernel<<<(E + 255) / 256, 256, 0, stream>>>(edge_attr, cols, aaaaa, w, pk, E);
    prep_kernel<<<(N + 255) / 256, 256, 0, stream>>>(pk, cnt, dinv, N);

    scan1<<<SCAN_NB, 256, 0, stream>>>(cnt, spartial, N);
    scan2<<<1, 64, 0, stream>>>(spartial, SCAN_NB);
    scan3<<<SCAN_NB, 256, 0, stream>>>(cnt, spartial, startA, cursor, N);
    place_kernel<<<(E + 255) / 256, 256, 0, stream>>>(rows, cols, w, dinv, cursor, rec, E);
    // after place: cursor[n] == end offset of node n

    const float* Wm[3]  = {W1, W2, W3};
    const float* bs[3]  = {b1, b2, b3};
    const float* wgs[3] = {wg1, wg2, wg3};
    const float* bgs[3] = {bg1, bg2, bg3};

    for (int l = 0; l < 3; l++) {
        if (l == 0)
            gemm64<float><<<(N + 255) / 256, 256, 0, stream>>>(x, Wm[l], bufB, N);
        else
            gemm64<bf16_t><<<(N + 255) / 256, 256, 0, stream>>>(bufA, Wm[l], bufB, N);
        gather_pool_kernel<<<GATHER_BLOCKS, 256, 0, stream>>>(
            bufB, startA, cursor, rec, dinv, bs[l], wgs[l], bgs[l],
            bufA, poolpart + (size_t)l * 65 * GATHER_BLOCKS, N);
    }

    pool_reduce<<<(3 * 65 * 64 + 255) / 256, 256, 0, stream>>>(poolpart, acc);
    finalize_kernel<<<1, 192, 0, stream>>>(acc, out);
}

// Round 5
// 519.874 us; speedup vs baseline: 7.3537x; 1.0659x over previous
//
#include <hip/hip_runtime.h>
#include <hip/hip_bf16.h>
#include <math.h>

#define HIDDEN    64
#define N_NODES   100000
#define N_EDGES   1250000
#define EDGE_FEAT 13

#define GATHER_BLOCKS 2048          // 8192 waves

typedef unsigned short bf16_t;
typedef unsigned char  u8;
typedef unsigned short u16;

static __device__ __forceinline__ float bf2f(bf16_t u) {
    union { unsigned int i; float f; } x; x.i = ((unsigned int)u) << 16; return x.f;
}
static __device__ __forceinline__ bf16_t f2bf(float f) {
    union { float f; unsigned int i; } u; u.f = f;
    unsigned int r = u.i + 0x7FFFu + ((u.i >> 16) & 1u);   // RNE
    return (bf16_t)(r >> 16);
}

// fp8 e4m3fn encode, RNE, saturate to 448 (values here are O(1); saturation never hit)
static __device__ __forceinline__ u8 f2fp8(float f) {
    union { float f; unsigned int u; } v; v.f = f;
    unsigned int s = (v.u >> 31) << 7;
    unsigned int mag = v.u & 0x7fffffffu;
    if (mag >= 0x43E80000u) return (u8)(s | 0x7Eu);          // >= 464 -> 448
    if (mag < 0x3C800000u) {                                 // < 2^-6: subnormal
        union { unsigned int u; float f; } t; t.u = mag;
        int qi = (int)rintf(t.f * 512.0f);                   // units of 2^-9; 8 == min normal
        return (u8)(s | (unsigned int)qi);
    }
    unsigned int r = mag + 0x7FFFFu + ((mag >> 20) & 1u);    // RNE at 3 mantissa bits
    unsigned int e8 = (r >> 23) - 120u;
    unsigned int m3 = (r >> 20) & 7u;
    return (u8)(s | (e8 << 3) | m3);
}

// ---------------- workspace layout (bytes) ----------------
#define OFF_CNT    0            // cnt  : N ints              (400,000)
#define OFF_START  400000       // start: N ints              (400,000)
#define OFF_PART   800000       // scan partials: 128 ints    (512)
#define OFF_DINV   800512       // dinv : N floats            (400,000)
#define OFF_ACC    1200512      // acc  : 3*65 floats         (pad 1024)
#define OFF_POOLP  1201536      // poolpart: 3*65*2048 floats (1,597,440)
#define OFF_RANK   2798976      // rank : E u16               (2,500,000)
#define OFF_WE     5298976      // w    : E floats            (5,000,000)
#define OFF_REC    10298976     // rec  : E int2 (row,w)      (10,000,000)
#define OFF_H8     20298976     // h8   : N*64 fp8            (6,400,000)
#define OFF_A      26698976     // bufA : N*64 bf16           (12,800,000)
// total = 39.5 MB

// w[e] = edge_attr . softmax(aaaaa) (LDS-coalesced); rank[e] = atomic rank among dest c
__global__ __launch_bounds__(256) void edgew_kernel(
    const float* __restrict__ attr, const int* __restrict__ cols,
    const float* __restrict__ aaaaa, float* __restrict__ w,
    u16* __restrict__ rank, int* __restrict__ cnt, int E)
{
    __shared__ float lds[EDGE_FEAT * 256];
    __shared__ float s[16];
    int t = threadIdx.x;
    if (t == 0) {
        float m = -1e30f;
        for (int i = 0; i < EDGE_FEAT; i++) m = fmaxf(m, aaaaa[i]);
        float ex[EDGE_FEAT]; float sum = 0.f;
        for (int i = 0; i < EDGE_FEAT; i++) { ex[i] = __expf(aaaaa[i] - m); sum += ex[i]; }
        float inv = 1.f / sum;
        for (int i = 0; i < EDGE_FEAT; i++) s[i] = ex[i] * inv;
    }
    int base_e = blockIdx.x * 256;
    size_t base = (size_t)base_e * EDGE_FEAT;
    int limit = (min(256, E - base_e)) * EDGE_FEAT;
#pragma unroll
    for (int j = 0; j < EDGE_FEAT; j++) {
        int idx = t + j * 256;
        if (idx < limit) lds[idx] = attr[base + idx];
    }
    __syncthreads();
    int e = base_e + t;
    if (e >= E) return;
    float acc = 0.f;
    const float* row = &lds[t * EDGE_FEAT];
#pragma unroll
    for (int f = 0; f < EDGE_FEAT; f++) acc = fmaf(row[f], s[f], acc);
    w[e] = acc;
    int c = cols[e];
    int rk = atomicAdd(&cnt[c], 1);
    rank[e] = (u16)rk;
}

// ---- 3-kernel exclusive scan over cnt[N] -> start[N] ----
#define SCAN_CHUNK 1024
#define SCAN_NB    ((N_NODES + SCAN_CHUNK - 1) / SCAN_CHUNK)   // 98

__global__ void scan1(const int* __restrict__ cnt, int* __restrict__ partial, int N) {
    __shared__ int s[256];
    int b = blockIdx.x, t = threadIdx.x;
    int base = b * SCAN_CHUNK + t * 4;
    int sum = 0;
#pragma unroll
    for (int i = 0; i < 4; i++) { int idx = base + i; if (idx < N) sum += cnt[idx]; }
    s[t] = sum; __syncthreads();
    for (int off = 128; off > 0; off >>= 1) {
        if (t < off) s[t] += s[t + off];
        __syncthreads();
    }
    if (t == 0) partial[b] = s[0];
}

__global__ void scan2(int* __restrict__ partial, int nb) {
    int lane = threadIdx.x;   // 64 threads
    int v0 = (lane < nb) ? partial[lane] : 0;
    int v1 = (lane + 64 < nb) ? partial[lane + 64] : 0;
    int s0 = v0;
#pragma unroll
    for (int m = 1; m < 64; m <<= 1) { int t = __shfl_up(s0, m, 64); if (lane >= m) s0 += t; }
    int total0 = __shfl(s0, 63, 64);
    int s1 = v1;
#pragma unroll
    for (int m = 1; m < 64; m <<= 1) { int t = __shfl_up(s1, m, 64); if (lane >= m) s1 += t; }
    if (lane < nb) partial[lane] = s0 - v0;
    if (lane + 64 < nb) partial[lane + 64] = total0 + s1 - v1;
}

__global__ void scan3(const int* __restrict__ cnt, const int* __restrict__ partial,
                      int* __restrict__ start, int N) {
    __shared__ int s[256];
    int b = blockIdx.x, t = threadIdx.x;
    int base = b * SCAN_CHUNK + t * 4;
    int v[4]; int sum = 0;
#pragma unroll
    for (int i = 0; i < 4; i++) { int idx = base + i; v[i] = (idx < N) ? cnt[idx] : 0; sum += v[i]; }
    s[t] = sum; __syncthreads();
    for (int off = 1; off < 256; off <<= 1) {
        int x = (t >= off) ? s[t - off] : 0;
        __syncthreads();
        s[t] += x;
        __syncthreads();
    }
    int excl = (t == 0) ? 0 : s[t - 1];
    int off0 = partial[b] + excl;
#pragma unroll
    for (int i = 0; i < 4; i++) {
        int idx = base + i;
        if (idx < N) { start[idx] = off0; off0 += v[i]; }
    }
}

// scatter edges into destination-sorted order; NO atomics (slot = start[c] + rank[e])
__global__ void place_kernel(const int* __restrict__ rows, const int* __restrict__ cols,
                             const float* __restrict__ w, const u16* __restrict__ rank,
                             const int* __restrict__ start, int2* __restrict__ rec, int E) {
    int e = blockIdx.x * blockDim.x + threadIdx.x;
    if (e >= E) return;
    int r = rows[e], c = cols[e];
    int slot = start[c] + (int)rank[e];
    rec[slot] = make_int2(r, __float_as_int(w[e]));
}

// deg[n] = 1 + sum of w over node n's rec segment; dinv = rsqrt(deg). No atomics.
__global__ void deginv_kernel(const int* __restrict__ start, const int* __restrict__ cnt,
                              const int2* __restrict__ rec, float* __restrict__ dinv, int N) {
    int n = blockIdx.x * blockDim.x + threadIdx.x;
    if (n >= N) return;
    int s = start[n], c = cnt[n];
    float d = 1.0f;
    for (int k = s; k < s + c; k++) d += __int_as_float(rec[k].y);
    dinv[n] = rsqrtf(d);
}

// ---- feature-type abstraction for gemm input ----
template <typename T> struct Feat;
template <> struct Feat<float> {
    static __device__ __forceinline__ float4 ld4(const float* A, size_t off) {
        return *(const float4*)(A + off);
    }
};
template <> struct Feat<bf16_t> {
    static __device__ __forceinline__ float4 ld4(const bf16_t* A, size_t off) {
        uint2 v = *(const uint2*)(A + off);
        float4 r;
        r.x = bf2f((bf16_t)(v.x & 0xffffu));
        r.y = bf2f((bf16_t)(v.x >> 16));
        r.z = bf2f((bf16_t)(v.y & 0xffffu));
        r.w = bf2f((bf16_t)(v.y >> 16));
        return r;
    }
};

// H8 = fp8(dinv[row] * (A @ W)) : 256 rows/block, 4 rows x 16 cols per thread
template <typename TIn>
__global__ __launch_bounds__(256) void gemm64(const TIn* __restrict__ A,
                                              const float* __restrict__ W,
                                              const float* __restrict__ dinv,
                                              u8* __restrict__ H8, int N) {
    __shared__ float Ws[HIDDEN * HIDDEN];
    int tid = threadIdx.x;
    {
        const float4* Wv = (const float4*)W;
        float4* Sv = (float4*)Ws;
#pragma unroll
        for (int i = 0; i < 4; i++) Sv[tid + 256 * i] = Wv[tid + 256 * i];
    }
    __syncthreads();
    int rg = tid >> 2;                 // 0..63
    int c0 = (tid & 3) * 16;
    int rbase = blockIdx.x * 256 + rg; // rows: rbase + 64*i
    int rld[4];
    bool rok[4];
#pragma unroll
    for (int i = 0; i < 4; i++) {
        int r = rbase + 64 * i;
        rok[i] = (r < N);
        rld[i] = rok[i] ? r : 0;
    }
    float acc[4][16];
#pragma unroll
    for (int i = 0; i < 4; i++)
#pragma unroll
        for (int j = 0; j < 16; j++) acc[i][j] = 0.f;

    for (int k = 0; k < HIDDEN; k += 4) {
        float4 a4[4];
#pragma unroll
        for (int i = 0; i < 4; i++)
            a4[i] = Feat<TIn>::ld4(A, (size_t)rld[i] * HIDDEN + k);
#pragma unroll
        for (int kk = 0; kk < 4; kk++) {
            const float* wr = &Ws[(k + kk) * HIDDEN + c0];
            float4 W0 = *(const float4*)(wr);
            float4 W1 = *(const float4*)(wr + 4);
            float4 W2 = *(const float4*)(wr + 8);
            float4 W3 = *(const float4*)(wr + 12);
            float wv[16] = {W0.x, W0.y, W0.z, W0.w, W1.x, W1.y, W1.z, W1.w,
                            W2.x, W2.y, W2.z, W2.w, W3.x, W3.y, W3.z, W3.w};
#pragma unroll
            for (int i = 0; i < 4; i++) {
                float ak[4] = {a4[i].x, a4[i].y, a4[i].z, a4[i].w};
                float av = ak[kk];
#pragma unroll
                for (int j = 0; j < 16; j++) acc[i][j] = fmaf(av, wv[j], acc[i][j]);
            }
        }
    }
#pragma unroll
    for (int i = 0; i < 4; i++) {
        if (!rok[i]) continue;
        float dv = dinv[rld[i]];
        unsigned int wd[4];
#pragma unroll
        for (int q = 0; q < 4; q++) {
            unsigned int b0 = f2fp8(dv * acc[i][4*q]);
            unsigned int b1 = f2fp8(dv * acc[i][4*q+1]);
            unsigned int b2 = f2fp8(dv * acc[i][4*q+2]);
            unsigned int b3 = f2fp8(dv * acc[i][4*q+3]);
            wd[q] = b0 | (b1 << 8) | (b2 << 16) | (b3 << 24);
        }
        *(uint4*)(H8 + (size_t)rld[i] * HIDDEN + c0) = make_uint4(wd[0], wd[1], wd[2], wd[3]);
    }
}

// one wave per node (grid-stride): out = relu(dinv[n]*(sum_e w*hs[r] + hs[n]) + b), fused pool
__global__ __launch_bounds__(256) void gather_pool_kernel(
    const u8* __restrict__ h8,
    const int* __restrict__ start, const int* __restrict__ cnt,
    const int2* __restrict__ rec,
    const float* __restrict__ dinv, const float* __restrict__ bias,
    const float* __restrict__ wg, const float* __restrict__ bg,
    bf16_t* __restrict__ out, float* __restrict__ poolpart, int N)
{
    __shared__ float lut[256];
    __shared__ float sred[4][65];
    {
        unsigned int b = threadIdx.x;
        unsigned int sg = b >> 7, ex = (b >> 3) & 0xF, m = b & 7;
        float mag;
        if (ex == 0) mag = (float)m * (1.0f / 512.0f);
        else { union { unsigned int u; float f; } q; q.u = ((ex + 120u) << 23) | (m << 20); mag = q.f; }
        lut[b] = sg ? -mag : mag;
    }
    __syncthreads();
    int lane = threadIdx.x & 63;
    int wid  = threadIdx.x >> 6;
    int wave = blockIdx.x * 4 + wid;
    const int nwaves = GATHER_BLOCKS * 4;
    float wgv = wg[lane];
    float bg0 = bg[0];
    float bv  = bias[lane];
    float accv = 0.f, accs = 0.f;

    for (int n = wave; n < N; n += nwaves) {
        float di = dinv[n];
        float a0 = lut[h8[(size_t)n * HIDDEN + lane]];   // self-loop term hs[n]
        float a1 = 0.f, a2 = 0.f, a3 = 0.f;
        int s = start[n], e = s + cnt[n];
        int k = s;
        for (; k + 8 <= e; k += 8) {
            int2 r[8];
#pragma unroll
            for (int j = 0; j < 8; j++) r[j] = rec[k + j];
            float hv[8];
#pragma unroll
            for (int j = 0; j < 8; j++) hv[j] = lut[h8[(size_t)r[j].x * HIDDEN + lane]];
            a0 = fmaf(__int_as_float(r[0].y), hv[0], a0);
            a1 = fmaf(__int_as_float(r[1].y), hv[1], a1);
            a2 = fmaf(__int_as_float(r[2].y), hv[2], a2);
            a3 = fmaf(__int_as_float(r[3].y), hv[3], a3);
            a0 = fmaf(__int_as_float(r[4].y), hv[4], a0);
            a1 = fmaf(__int_as_float(r[5].y), hv[5], a1);
            a2 = fmaf(__int_as_float(r[6].y), hv[6], a2);
            a3 = fmaf(__int_as_float(r[7].y), hv[7], a3);
        }
        for (; k < e; k++) {
            int2 r = rec[k];
            a0 = fmaf(__int_as_float(r.y), lut[h8[(size_t)r.x * HIDDEN + lane]], a0);
        }
        float v = fmaxf(fmaf(di, (a0 + a1) + (a2 + a3), bv), 0.f);
        out[(size_t)n * HIDDEN + lane] = f2bf(v);
        // attention-pool contribution
        float p = v * wgv;
#pragma unroll
        for (int m = 32; m > 0; m >>= 1) p += __shfl_xor(p, m, 64);
        float g = 1.f / (1.f + __expf(-(p + bg0)));
        float eg = __expf(g);
        accv = fmaf(eg, v, accv);
        accs += eg;
    }

    sred[wid][lane] = accv;
    if (lane == 0) sred[wid][64] = accs;
    __syncthreads();
    if (wid == 0) {
        float s0 = sred[0][lane] + sred[1][lane] + sred[2][lane] + sred[3][lane];
        poolpart[(size_t)lane * GATHER_BLOCKS + blockIdx.x] = s0;
        if (lane == 0) {
            float ss = sred[0][64] + sred[1][64] + sred[2][64] + sred[3][64];
            poolpart[(size_t)64 * GATHER_BLOCKS + blockIdx.x] = ss;
        }
    }
}

// one wave per (layer, entry): sum 2048 block partials -> acc[3*65]
__global__ void pool_reduce(const float* __restrict__ poolpart, float* __restrict__ acc) {
    int entry = (int)((blockIdx.x * blockDim.x + threadIdx.x) >> 6);  // 0..194
    int lane = threadIdx.x & 63;
    if (entry >= 3 * 65) return;
    const float* p = poolpart + (size_t)entry * GATHER_BLOCKS;
    float s = 0.f;
    for (int i = lane; i < GATHER_BLOCKS; i += 64) s += p[i];
#pragma unroll
    for (int m = 32; m > 0; m >>= 1) s += __shfl_xor(s, m, 64);
    if (lane == 0) acc[entry] = s;
}

__global__ void finalize_kernel(const float* __restrict__ acc, float* __restrict__ out) {
    int i = threadIdx.x;  // 192 threads
    if (i >= 3 * HIDDEN) return;
    int layer = i >> 6, c = i & 63;
    const float* a = acc + layer * 65;
    out[i] = a[c] / a[64];
}

extern "C" void kernel_launch(void* const* d_in, const int* in_sizes, int n_in,
                              void* d_out, int out_size, void* d_ws, size_t ws_size,
                              hipStream_t stream) {
    const float* x          = (const float*)d_in[0];
    const int*   edge_index = (const int*)  d_in[1];   // [2,E] flat: rows then cols
    const float* edge_attr  = (const float*)d_in[2];
    const float* aaaaa      = (const float*)d_in[3];
    const float* W1 = (const float*)d_in[4];  const float* b1 = (const float*)d_in[5];
    const float* W2 = (const float*)d_in[6];  const float* b2 = (const float*)d_in[7];
    const float* W3 = (const float*)d_in[8];  const float* b3 = (const float*)d_in[9];
    const float* wg1 = (const float*)d_in[10]; const float* bg1 = (const float*)d_in[11];
    const float* wg2 = (const float*)d_in[12]; const float* bg2 = (const float*)d_in[13];
    const float* wg3 = (const float*)d_in[14]; const float* bg3 = (const float*)d_in[15];
    float* out = (float*)d_out;

    char* ws = (char*)d_ws;
    int*    cnt      = (int*)   (ws + OFF_CNT);
    int*    startA   = (int*)   (ws + OFF_START);
    int*    spartial = (int*)   (ws + OFF_PART);
    float*  dinv     = (float*) (ws + OFF_DINV);
    float*  acc      = (float*) (ws + OFF_ACC);
    float*  poolpart = (float*) (ws + OFF_POOLP);
    u16*    rankA    = (u16*)   (ws + OFF_RANK);
    float*  wE       = (float*) (ws + OFF_WE);
    int2*   rec      = (int2*)  (ws + OFF_REC);
    u8*     h8       = (u8*)    (ws + OFF_H8);
    bf16_t* bufA     = (bf16_t*)(ws + OFF_A);

    const int* rows = edge_index;
    const int* cols = edge_index + N_EDGES;
    const int N = N_NODES, E = N_EDGES;

    hipMemsetAsync(cnt, 0, N * sizeof(int), stream);
    edgew_kernel<<<(E + 255) / 256, 256, 0, stream>>>(edge_attr, cols, aaaaa, wE, rankA, cnt, E);

    scan1<<<SCAN_NB, 256, 0, stream>>>(cnt, spartial, N);
    scan2<<<1, 64, 0, stream>>>(spartial, SCAN_NB);
    scan3<<<SCAN_NB, 256, 0, stream>>>(cnt, spartial, startA, N);
    place_kernel<<<(E + 255) / 256, 256, 0, stream>>>(rows, cols, wE, rankA, startA, rec, E);
    deginv_kernel<<<(N + 255) / 256, 256, 0, stream>>>(startA, cnt, rec, dinv, N);

    const float* Wm[3]  = {W1, W2, W3};
    const float* bs[3]  = {b1, b2, b3};
    const float* wgs[3] = {wg1, wg2, wg3};
    const float* bgs[3] = {bg1, bg2, bg3};

    for (int l = 0; l < 3; l++) {
        if (l == 0)
            gemm64<float><<<(N + 255) / 256, 256, 0, stream>>>(x, Wm[l], dinv, h8, N);
        else
            gemm64<bf16_t><<<(N + 255) / 256, 256, 0, stream>>>(bufA, Wm[l], dinv, h8, N);
        gather_pool_kernel<<<GATHER_BLOCKS, 256, 0, stream>>>(
            h8, startA, cnt, rec, dinv, bs[l], wgs[l], bgs[l],
            bufA, poolpart + (size_t)l * 65 * GATHER_BLOCKS, N);
    }

    pool_reduce<<<(3 * 65 * 64 + 255) / 256, 256, 0, stream>>>(poolpart, acc);
    finalize_kernel<<<1, 192, 0, stream>>>(acc, out);
}

// Round 7
// 517.391 us; speedup vs baseline: 7.3890x; 1.0048x over previous
//
#include <hip/hip_runtime.h>
#include <hip/hip_bf16.h>
#include <math.h>

#define HIDDEN    64
#define N_NODES   100000
#define N_EDGES   1250000
#define EDGE_FEAT 13

#define GATHER_BLOCKS 2048          // 8192 waves
#define EDGEW_NB  ((N_EDGES + 255) / 256)   // 4883
#define GEMM_NB   ((N_NODES + 255) / 256)   // 391
#define K1_NB     5291              // 407 gemm-role (391 active) + 4884 edgew-role (4883 active)

typedef unsigned short bf16_t;
typedef unsigned char  u8;
typedef unsigned short u16;

static __device__ __forceinline__ float bf2f(bf16_t u) {
    union { unsigned int i; float f; } x; x.i = ((unsigned int)u) << 16; return x.f;
}
static __device__ __forceinline__ bf16_t f2bf(float f) {
    union { float f; unsigned int i; } u; u.f = f;
    unsigned int r = u.i + 0x7FFFu + ((u.i >> 16) & 1u);   // RNE
    return (bf16_t)(r >> 16);
}

// fp8 e4m3fn encode, RNE, saturate to 448
static __device__ __forceinline__ u8 f2fp8(float f) {
    union { float f; unsigned int u; } v; v.f = f;
    unsigned int s = (v.u >> 31) << 7;
    unsigned int mag = v.u & 0x7fffffffu;
    if (mag >= 0x43E80000u) return (u8)(s | 0x7Eu);          // >= 464 -> 448
    if (mag < 0x3C800000u) {                                 // < 2^-6: subnormal
        union { unsigned int u; float f; } t; t.u = mag;
        int qi = (int)rintf(t.f * 512.0f);
        return (u8)(s | (unsigned int)qi);
    }
    unsigned int r = mag + 0x7FFFFu + ((mag >> 20) & 1u);    // RNE at 3 mantissa bits
    unsigned int e8 = (r >> 23) - 120u;
    unsigned int m3 = (r >> 20) & 7u;
    return (u8)(s | (e8 << 3) | m3);
}

// ---------------- workspace layout (bytes) ----------------
#define OFF_CNT8   0            // cnt8 : 8N ints   (3,200,000)
#define OFF_BASE8  3200000      // base8: 8N ints   (3,200,000)
#define OFF_START  6400000      // start: N ints    (400,000)
#define OFF_PART   6800000      // scan partials    (512)
#define OFF_DINV   6800512      // dinv : N floats  (400,000)
#define OFF_ACC    7200512      // acc  : 3*65 f    (pad 1024)
#define OFF_POOLP  7201536      // poolpart         (1,597,440)
#define OFF_RANK   8798976      // rank : E u16     (2,500,000)
#define OFF_WE     11298976     // w    : E floats  (5,000,000)
#define OFF_REC    16298976     // rec  : E int2    (10,000,000)
#define OFF_H8     26298976     // h8   : N*64 fp8  (6,400,000)
#define OFF_A      32698976     // bufA : N*64 bf16 (12,800,000)
// total = 45.5 MB

// ---- feature-type abstraction for gemm input ----
template <typename T> struct Feat;
template <> struct Feat<float> {
    static __device__ __forceinline__ float4 ld4(const float* A, size_t off) {
        return *(const float4*)(A + off);
    }
};
template <> struct Feat<bf16_t> {
    static __device__ __forceinline__ float4 ld4(const bf16_t* A, size_t off) {
        uint2 v = *(const uint2*)(A + off);
        float4 r;
        r.x = bf2f((bf16_t)(v.x & 0xffffu));
        r.y = bf2f((bf16_t)(v.x >> 16));
        r.z = bf2f((bf16_t)(v.y & 0xffffu));
        r.w = bf2f((bf16_t)(v.y >> 16));
        return r;
    }
};

// H8 = fp8(A @ W), UNSCALED. 256 rows per call-block, 4 rows x 16 cols per thread.
template <typename TIn>
static __device__ __forceinline__ void gemm_body(int gb, const TIn* __restrict__ A,
                                                 const float* __restrict__ W,
                                                 u8* __restrict__ H8, float* smem,
                                                 int tid, int N) {
    {
        const float4* Wv = (const float4*)W;
        float4* Sv = (float4*)smem;
#pragma unroll
        for (int i = 0; i < 4; i++) Sv[tid + 256 * i] = Wv[tid + 256 * i];
    }
    __syncthreads();
    int rg = tid >> 2;
    int c0 = (tid & 3) * 16;
    int rbase = gb * 256 + rg;
    int rld[4]; bool rok[4];
#pragma unroll
    for (int i = 0; i < 4; i++) {
        int r = rbase + 64 * i;
        rok[i] = (r < N);
        rld[i] = rok[i] ? r : 0;
    }
    float acc[4][16];
#pragma unroll
    for (int i = 0; i < 4; i++)
#pragma unroll
        for (int j = 0; j < 16; j++) acc[i][j] = 0.f;

    for (int k = 0; k < HIDDEN; k += 4) {
        float4 a4[4];
#pragma unroll
        for (int i = 0; i < 4; i++)
            a4[i] = Feat<TIn>::ld4(A, (size_t)rld[i] * HIDDEN + k);
#pragma unroll
        for (int kk = 0; kk < 4; kk++) {
            const float* wr = &smem[(k + kk) * HIDDEN + c0];
            float4 W0 = *(const float4*)(wr);
            float4 W1 = *(const float4*)(wr + 4);
            float4 W2 = *(const float4*)(wr + 8);
            float4 W3 = *(const float4*)(wr + 12);
            float wv[16] = {W0.x, W0.y, W0.z, W0.w, W1.x, W1.y, W1.z, W1.w,
                            W2.x, W2.y, W2.z, W2.w, W3.x, W3.y, W3.z, W3.w};
#pragma unroll
            for (int i = 0; i < 4; i++) {
                float ak[4] = {a4[i].x, a4[i].y, a4[i].z, a4[i].w};
                float av = ak[kk];
#pragma unroll
                for (int j = 0; j < 16; j++) acc[i][j] = fmaf(av, wv[j], acc[i][j]);
            }
        }
    }
#pragma unroll
    for (int i = 0; i < 4; i++) {
        if (!rok[i]) continue;
        unsigned int wd[4];
#pragma unroll
        for (int q = 0; q < 4; q++) {
            unsigned int b0 = f2fp8(acc[i][4*q]);
            unsigned int b1 = f2fp8(acc[i][4*q+1]);
            unsigned int b2 = f2fp8(acc[i][4*q+2]);
            unsigned int b3 = f2fp8(acc[i][4*q+3]);
            wd[q] = b0 | (b1 << 8) | (b2 << 16) | (b3 << 24);
        }
        *(uint4*)(H8 + (size_t)rld[i] * HIDDEN + c0) = make_uint4(wd[0], wd[1], wd[2], wd[3]);
    }
}

// edgew body: w[e], 8-way split histogram atomic, rank = (hist<<12)|subrank
static __device__ __forceinline__ void edgew_body(int eb, int hist,
    const float* __restrict__ attr, const int* __restrict__ cols,
    const float* __restrict__ aaaaa, float* __restrict__ w,
    u16* __restrict__ rank, int* __restrict__ cnt8, float* smem, int t, int E)
{
    float* lds = smem;                     // 13*256 floats
    float* s   = smem + EDGE_FEAT * 256;   // 16 floats
    if (t == 0) {
        float m = -1e30f;
        for (int i = 0; i < EDGE_FEAT; i++) m = fmaxf(m, aaaaa[i]);
        float ex[EDGE_FEAT]; float sum = 0.f;
        for (int i = 0; i < EDGE_FEAT; i++) { ex[i] = __expf(aaaaa[i] - m); sum += ex[i]; }
        float inv = 1.f / sum;
        for (int i = 0; i < EDGE_FEAT; i++) s[i] = ex[i] * inv;
    }
    int base_e = eb * 256;
    size_t base = (size_t)base_e * EDGE_FEAT;
    int limit = (min(256, E - base_e)) * EDGE_FEAT;
#pragma unroll
    for (int j = 0; j < EDGE_FEAT; j++) {
        int idx = t + j * 256;
        if (idx < limit) lds[idx] = attr[base + idx];
    }
    int e = base_e + t;
    int c = (e < E) ? cols[e] : 0;
    int rk = 0;
    if (e < E) rk = atomicAdd(&cnt8[hist * N_NODES + c], 1);   // issue early, overlap below
    __syncthreads();
    if (e >= E) return;
    float acc = 0.f;
    const float* row = &lds[t * EDGE_FEAT];
#pragma unroll
    for (int f = 0; f < EDGE_FEAT; f++) acc = fmaf(row[f], s[f], acc);
    w[e] = acc;
    rank[e] = (u16)((hist << 12) | rk);
}

// fused: edgew blocks + gemm1 blocks (every 13th block is gemm-role)
__global__ __launch_bounds__(256) void build_gemm1_kernel(
    const float* __restrict__ attr, const int* __restrict__ cols,
    const float* __restrict__ aaaaa, float* __restrict__ w,
    u16* __restrict__ rank, int* __restrict__ cnt8,
    const float* __restrict__ x, const float* __restrict__ W1,
    u8* __restrict__ H8, int E, int N)
{
    __shared__ float smem[HIDDEN * HIDDEN];   // 16 KB; edgew uses 3344 floats of it
    int bid = blockIdx.x;
    int g = bid / 13;
    if (bid % 13 == 0) {
        if (g < GEMM_NB) gemm_body<float>(g, x, W1, H8, smem, threadIdx.x, N);
        return;
    }
    int eb = bid - g - 1;
    if (eb >= EDGEW_NB) return;
    edgew_body(eb, bid & 7, attr, cols, aaaaa, w, rank, cnt8, smem, threadIdx.x, E);
}

// standalone gemm for layers 2,3
__global__ __launch_bounds__(256) void gemm64(const bf16_t* __restrict__ A,
                                              const float* __restrict__ W,
                                              u8* __restrict__ H8, int N) {
    __shared__ float smem[HIDDEN * HIDDEN];
    gemm_body<bf16_t>(blockIdx.x, A, W, H8, smem, threadIdx.x, N);
}

// ---- 3-kernel exclusive scan over per-node totals -> start[N], base8[8][N] ----
#define SCAN_CHUNK 1024
#define SCAN_NB    ((N_NODES + SCAN_CHUNK - 1) / SCAN_CHUNK)   // 98

__global__ void scan1(const int* __restrict__ cnt8, int* __restrict__ partial, int N) {
    __shared__ int s[256];
    int b = blockIdx.x, t = threadIdx.x;
    int base = b * SCAN_CHUNK + t * 4;
    int sum = 0;
#pragma unroll
    for (int i = 0; i < 4; i++) {
        int idx = base + i;
        if (idx < N) {
#pragma unroll
            for (int h = 0; h < 8; h++) sum += cnt8[h * N_NODES + idx];
        }
    }
    s[t] = sum; __syncthreads();
    for (int off = 128; off > 0; off >>= 1) {
        if (t < off) s[t] += s[t + off];
        __syncthreads();
    }
    if (t == 0) partial[b] = s[0];
}

__global__ void scan2(int* __restrict__ partial, int nb) {
    int lane = threadIdx.x;   // 64 threads
    int v0 = (lane < nb) ? partial[lane] : 0;
    int v1 = (lane + 64 < nb) ? partial[lane + 64] : 0;
    int s0 = v0;
#pragma unroll
    for (int m = 1; m < 64; m <<= 1) { int t = __shfl_up(s0, m, 64); if (lane >= m) s0 += t; }
    int total0 = __shfl(s0, 63, 64);
    int s1 = v1;
#pragma unroll
    for (int m = 1; m < 64; m <<= 1) { int t = __shfl_up(s1, m, 64); if (lane >= m) s1 += t; }
    if (lane < nb) partial[lane] = s0 - v0;
    if (lane + 64 < nb) partial[lane + 64] = total0 + s1 - v1;
}

__global__ void scan3(const int* __restrict__ cnt8, const int* __restrict__ partial,
                      int* __restrict__ start, int* __restrict__ base8, int N) {
    __shared__ int s[256];
    int b = blockIdx.x, t = threadIdx.x;
    int base = b * SCAN_CHUNK + t * 4;
    int v[4]; int sum = 0;
#pragma unroll
    for (int i = 0; i < 4; i++) {
        int idx = base + i; int tot = 0;
        if (idx < N) {
#pragma unroll
            for (int h = 0; h < 8; h++) tot += cnt8[h * N_NODES + idx];
        }
        v[i] = tot; sum += tot;
    }
    s[t] = sum; __syncthreads();
    for (int off = 1; off < 256; off <<= 1) {
        int x = (t >= off) ? s[t - off] : 0;
        __syncthreads();
        s[t] += x;
        __syncthreads();
    }
    int excl = (t == 0) ? 0 : s[t - 1];
    int off0 = partial[b] + excl;
#pragma unroll
    for (int i = 0; i < 4; i++) {
        int idx = base + i;
        if (idx < N) {
            start[idx] = off0;
            int run = off0;
#pragma unroll
            for (int h = 0; h < 8; h++) {
                base8[h * N_NODES + idx] = run;
                run += cnt8[h * N_NODES + idx];
            }
            off0 += v[i];
        }
    }
}

// scatter edges into destination-sorted order; NO atomics
__global__ void place_kernel(const int* __restrict__ rows, const int* __restrict__ cols,
                             const float* __restrict__ w, const u16* __restrict__ rank,
                             const int* __restrict__ base8, int2* __restrict__ rec, int E) {
    int e = blockIdx.x * blockDim.x + threadIdx.x;
    if (e >= E) return;
    int r = rows[e], c = cols[e];
    u16 rk = rank[e];
    int slot = base8[(int)(rk >> 12) * N_NODES + c] + (int)(rk & 0xFFF);
    rec[slot] = make_int2(r, __float_as_int(w[e]));
}

// dinv[n] = rsqrt(1 + sum of w over segment); wave per node
__global__ __launch_bounds__(256) void deginv_kernel(const int* __restrict__ start,
                                                     const int2* __restrict__ rec,
                                                     float* __restrict__ dinv, int N) {
    int lane = threadIdx.x & 63;
    int n = blockIdx.x * 4 + (threadIdx.x >> 6);
    if (n >= N) return;
    int s = start[n];
    int e = (n + 1 < N) ? start[n + 1] : N_EDGES;
    float d = 0.f;
    for (int k = s + lane; k < e; k += 64) d += __int_as_float(rec[k].y);
#pragma unroll
    for (int m = 32; m > 0; m >>= 1) d += __shfl_xor(d, m, 64);
    if (lane == 0) dinv[n] = rsqrtf(1.0f + d);
}

// rec.y = w * dinv[row] * dinv[col]; wave per node
__global__ __launch_bounds__(256) void scale_rec_kernel(const int* __restrict__ start,
                                                        const float* __restrict__ dinv,
                                                        int2* __restrict__ rec, int N) {
    int lane = threadIdx.x & 63;
    int n = blockIdx.x * 4 + (threadIdx.x >> 6);
    if (n >= N) return;
    float dc = dinv[n];
    int s = start[n];
    int e = (n + 1 < N) ? start[n + 1] : N_EDGES;
    for (int k = s + lane; k < e; k += 64) {
        int2 rr = rec[k];
        float nw = __int_as_float(rr.y) * dinv[rr.x] * dc;
        rec[k] = make_int2(rr.x, __float_as_int(nw));
    }
}

// one wave per node (grid-stride): out = relu(sum_e norm*h[r] + dinv^2*h[n] + b), fused pool
__global__ __launch_bounds__(256) void gather_pool_kernel(
    const u8* __restrict__ h8,
    const int* __restrict__ start,
    const int2* __restrict__ rec,
    const float* __restrict__ dinv, const float* __restrict__ bias,
    const float* __restrict__ wg, const float* __restrict__ bg,
    bf16_t* __restrict__ out, float* __restrict__ poolpart, int N)
{
    __shared__ float lut[256];
    __shared__ float sred[4][65];
    {
        unsigned int b = threadIdx.x;
        unsigned int sg = b >> 7, ex = (b >> 3) & 0xF, m = b & 7;
        float mag;
        if (ex == 0) mag = (float)m * (1.0f / 512.0f);
        else { union { unsigned int u; float f; } q; q.u = ((ex + 120u) << 23) | (m << 20); mag = q.f; }
        lut[b] = sg ? -mag : mag;
    }
    __syncthreads();
    int lane = threadIdx.x & 63;
    int wid  = threadIdx.x >> 6;
    int wave = blockIdx.x * 4 + wid;
    const int nwaves = GATHER_BLOCKS * 4;
    float wgv = wg[lane];
    float bg0 = bg[0];
    float bv  = bias[lane];
    float accv = 0.f, accs = 0.f;

    for (int n = wave; n < N; n += nwaves) {
        float di = dinv[n];
        int s = start[n];
        int e = (n + 1 < N) ? start[n + 1] : N_EDGES;
        float a0 = di * di * lut[h8[(size_t)n * HIDDEN + lane]];
        float a1 = 0.f, a2 = 0.f, a3 = 0.f;
        // masked unroll-8: always 8 gathers in flight (tail lanes clamp to e-1, weight 0)
        for (int k = s; k < e; k += 8) {
            int2 r[8]; float wt[8];
#pragma unroll
            for (int j = 0; j < 8; j++) {
                int kk = (k + j < e) ? (k + j) : (e - 1);
                r[j] = rec[kk];
                wt[j] = (k + j < e) ? __int_as_float(r[j].y) : 0.f;
            }
            float hv[8];
#pragma unroll
            for (int j = 0; j < 8; j++) hv[j] = lut[h8[(size_t)r[j].x * HIDDEN + lane]];
            a0 = fmaf(wt[0], hv[0], a0);
            a1 = fmaf(wt[1], hv[1], a1);
            a2 = fmaf(wt[2], hv[2], a2);
            a3 = fmaf(wt[3], hv[3], a3);
            a0 = fmaf(wt[4], hv[4], a0);
            a1 = fmaf(wt[5], hv[5], a1);
            a2 = fmaf(wt[6], hv[6], a2);
            a3 = fmaf(wt[7], hv[7], a3);
        }
        float v = fmaxf(((a0 + a1) + (a2 + a3)) + bv, 0.f);
        out[(size_t)n * HIDDEN + lane] = f2bf(v);
        float p = v * wgv;
#pragma unroll
        for (int m = 32; m > 0; m >>= 1) p += __shfl_xor(p, m, 64);
        float g = 1.f / (1.f + __expf(-(p + bg0)));
        float eg = __expf(g);
        accv = fmaf(eg, v, accv);
        accs += eg;
    }

    sred[wid][lane] = accv;
    if (lane == 0) sred[wid][64] = accs;
    __syncthreads();
    if (wid == 0) {
        float s0 = sred[0][lane] + sred[1][lane] + sred[2][lane] + sred[3][lane];
        poolpart[(size_t)lane * GATHER_BLOCKS + blockIdx.x] = s0;
        if (lane == 0) {
            float ss = sred[0][64] + sred[1][64] + sred[2][64] + sred[3][64];
            poolpart[(size_t)64 * GATHER_BLOCKS + blockIdx.x] = ss;
        }
    }
}

__global__ void pool_reduce(const float* __restrict__ poolpart, float* __restrict__ acc) {
    int entry = (int)((blockIdx.x * blockDim.x + threadIdx.x) >> 6);  // 0..194
    int lane = threadIdx.x & 63;
    if (entry >= 3 * 65) return;
    const float* p = poolpart + (size_t)entry * GATHER_BLOCKS;
    float s = 0.f;
    for (int i = lane; i < GATHER_BLOCKS; i += 64) s += p[i];
#pragma unroll
    for (int m = 32; m > 0; m >>= 1) s += __shfl_xor(s, m, 64);
    if (lane == 0) acc[entry] = s;
}

__global__ void finalize_kernel(const float* __restrict__ acc, float* __restrict__ out) {
    int i = threadIdx.x;  // 192 threads
    if (i >= 3 * HIDDEN) return;
    int layer = i >> 6, c = i & 63;
    const float* a = acc + layer * 65;
    out[i] = a[c] / a[64];
}

extern "C" void kernel_launch(void* const* d_in, const int* in_sizes, int n_in,
                              void* d_out, int out_size, void* d_ws, size_t ws_size,
                              hipStream_t stream) {
    const float* x          = (const float*)d_in[0];
    const int*   edge_index = (const int*)  d_in[1];   // [2,E] flat: rows then cols
    const float* edge_attr  = (const float*)d_in[2];
    const float* aaaaa      = (const float*)d_in[3];
    const float* W1 = (const float*)d_in[4];  const float* b1 = (const float*)d_in[5];
    const float* W2 = (const float*)d_in[6];  const float* b2 = (const float*)d_in[7];
    const float* W3 = (const float*)d_in[8];  const float* b3 = (const float*)d_in[9];
    const float* wg1 = (const float*)d_in[10]; const float* bg1 = (const float*)d_in[11];
    const float* wg2 = (const float*)d_in[12]; const float* bg2 = (const float*)d_in[13];
    const float* wg3 = (const float*)d_in[14]; const float* bg3 = (const float*)d_in[15];
    float* out = (float*)d_out;

    char* ws = (char*)d_ws;
    int*    cnt8     = (int*)   (ws + OFF_CNT8);
    int*    base8    = (int*)   (ws + OFF_BASE8);
    int*    startA   = (int*)   (ws + OFF_START);
    int*    spartial = (int*)   (ws + OFF_PART);
    float*  dinv     = (float*) (ws + OFF_DINV);
    float*  acc      = (float*) (ws + OFF_ACC);
    float*  poolpart = (float*) (ws + OFF_POOLP);
    u16*    rankA    = (u16*)   (ws + OFF_RANK);
    float*  wE       = (float*) (ws + OFF_WE);
    int2*   rec      = (int2*)  (ws + OFF_REC);
    u8*     h8       = (u8*)    (ws + OFF_H8);
    bf16_t* bufA     = (bf16_t*)(ws + OFF_A);

    const int* rows = edge_index;
    const int* cols = edge_index + N_EDGES;
    const int N = N_NODES, E = N_EDGES;

    (void)hipMemsetAsync(cnt8, 0, 8 * N * sizeof(int), stream);

    // fused: edge weights + 8-way histogram + gemm1 (x @ W1 -> h8, unscaled fp8)
    build_gemm1_kernel<<<K1_NB, 256, 0, stream>>>(edge_attr, cols, aaaaa, wE, rankA, cnt8,
                                                  x, W1, h8, E, N);

    scan1<<<SCAN_NB, 256, 0, stream>>>(cnt8, spartial, N);
    scan2<<<1, 64, 0, stream>>>(spartial, SCAN_NB);
    scan3<<<SCAN_NB, 256, 0, stream>>>(cnt8, spartial, startA, base8, N);
    place_kernel<<<(E + 255) / 256, 256, 0, stream>>>(rows, cols, wE, rankA, base8, rec, E);
    deginv_kernel<<<(N + 3) / 4, 256, 0, stream>>>(startA, rec, dinv, N);
    scale_rec_kernel<<<(N + 3) / 4, 256, 0, stream>>>(startA, dinv, rec, N);

    const float* Wm[3]  = {W1, W2, W3};
    const float* bs[3]  = {b1, b2, b3};
    const float* wgs[3] = {wg1, wg2, wg3};
    const float* bgs[3] = {bg1, bg2, bg3};

    for (int l = 0; l < 3; l++) {
        if (l > 0)
            gemm64<<<GEMM_NB, 256, 0, stream>>>(bufA, Wm[l], h8, N);
        gather_pool_kernel<<<GATHER_BLOCKS, 256, 0, stream>>>(
            h8, startA, rec, dinv, bs[l], wgs[l], bgs[l],
            bufA, poolpart + (size_t)l * 65 * GATHER_BLOCKS, N);
    }

    pool_reduce<<<(3 * 65 * 64 + 255) / 256, 256, 0, stream>>>(poolpart, acc);
    finalize_kernel<<<1, 192, 0, stream>>>(acc, out);
}